// Round 1
// baseline (4076.392 us; speedup 1.0000x reference)
//
#include <hip/hip_runtime.h>
#include <hip/hip_bf16.h>
#include <math.h>

#define IN_DIM 172
#define HID 128
#define TDIM 100

__device__ inline void atomicMaxF(float* addr, float val) {
  int old = __float_as_int(*addr);
  while (__int_as_float(old) < val) {
    int assumed = old;
    old = atomicCAS((int*)addr, assumed, __float_as_int(val));
    if (old == assumed) break;
  }
}

// h = relu(x_all[ids] @ Wp + bp), 8 rows/block
__global__ __launch_bounds__(256) void k_in_gemm(
    const float* __restrict__ x_all, const int* __restrict__ ids,
    const float* __restrict__ Wp, const float* __restrict__ bp,
    float* __restrict__ h, int n) {
  __shared__ float xs[8][IN_DIM];
  int r0 = blockIdx.x * 8;
  for (int idx = threadIdx.x; idx < 8 * IN_DIM; idx += 256) {
    int r = idx / IN_DIM, c = idx - r * IN_DIM;
    int row = r0 + r;
    xs[r][c] = (row < n) ? x_all[(size_t)ids[row] * IN_DIM + c] : 0.f;
  }
  __syncthreads();
  int col = threadIdx.x & 127;
  int rg = threadIdx.x >> 7;
  float acc[4] = {0.f, 0.f, 0.f, 0.f};
  #pragma unroll 4
  for (int kk = 0; kk < IN_DIM; ++kk) {
    float w = Wp[kk * HID + col];
    #pragma unroll
    for (int j = 0; j < 4; ++j) acc[j] += xs[rg + 2 * j][kk] * w;
  }
  float bias = bp[col];
  #pragma unroll
  for (int j = 0; j < 4; ++j) {
    int row = r0 + rg + 2 * j;
    if (row < n) {
      float v = acc[j] + bias;
      h[(size_t)row * HID + col] = v > 0.f ? v : 0.f;
    }
  }
}

// Y = X @ W + b (X: n x 128, W: 128 x 128), 8 rows/block
__global__ __launch_bounds__(256) void k_gemm128(
    const float* __restrict__ X, const float* __restrict__ W,
    const float* __restrict__ b, float* __restrict__ Y, int n) {
  __shared__ float xs[8][HID];
  int r0 = blockIdx.x * 8;
  for (int idx = threadIdx.x; idx < 8 * HID; idx += 256) {
    int r = idx >> 7, c = idx & 127;
    int row = r0 + r;
    xs[r][c] = (row < n) ? X[(size_t)row * HID + c] : 0.f;
  }
  __syncthreads();
  int col = threadIdx.x & 127;
  int rg = threadIdx.x >> 7;
  float acc[4] = {0.f, 0.f, 0.f, 0.f};
  #pragma unroll 4
  for (int kk = 0; kk < HID; ++kk) {
    float w = W[kk * HID + col];
    #pragma unroll
    for (int j = 0; j < 4; ++j) acc[j] += xs[rg + 2 * j][kk] * w;
  }
  float bias = b[col];
  #pragma unroll
  for (int j = 0; j < 4; ++j) {
    int row = r0 + rg + 2 * j;
    if (row < n) Y[(size_t)row * HID + col] = acc[j] + bias;
  }
}

// Y = X @ W + b (X: n x 128, W: 128 x 64), 16 rows/block
__global__ __launch_bounds__(256) void k_gemm_64(
    const float* __restrict__ X, const float* __restrict__ W,
    const float* __restrict__ b, float* __restrict__ Y, int n) {
  __shared__ float xs[16][HID];
  int r0 = blockIdx.x * 16;
  for (int idx = threadIdx.x; idx < 16 * HID; idx += 256) {
    int r = idx >> 7, c = idx & 127;
    int row = r0 + r;
    xs[r][c] = (row < n) ? X[(size_t)row * HID + c] : 0.f;
  }
  __syncthreads();
  int col = threadIdx.x & 63;
  int rg = threadIdx.x >> 6;
  float acc[4] = {0.f, 0.f, 0.f, 0.f};
  #pragma unroll 4
  for (int kk = 0; kk < HID; ++kk) {
    float w = W[kk * 64 + col];
    #pragma unroll
    for (int j = 0; j < 4; ++j) acc[j] += xs[rg + 4 * j][kk] * w;
  }
  float bias = b[col];
  #pragma unroll
  for (int j = 0; j < 4; ++j) {
    int row = r0 + rg + 4 * j;
    if (row < n) Y[(size_t)row * 64 + col] = acc[j] + bias;
  }
}

__global__ void k_init_ms(float* __restrict__ m, float* __restrict__ s, int count) {
  int i = blockIdx.x * 256 + threadIdx.x;
  if (i < count) { m[i] = -INFINITY; s[i] = 0.f; }
}

// pass 1: alpha[e][h] = q[dst].(k[src]+e)/sqrt(32); atomicMax m[dst][h]
__global__ __launch_bounds__(256) void k_edge_alpha(
    const int* __restrict__ src, const int* __restrict__ dst,
    const float* __restrict__ dts,
    const float* __restrict__ freq, const float* __restrict__ phase,
    const float* __restrict__ We,
    const float* __restrict__ q, const float* __restrict__ k,
    float* __restrict__ alpha, float* __restrict__ m, int nE) {
  __shared__ float wes[TDIM][HID];
  __shared__ float fr[TDIM], ph[TDIM];
  __shared__ float tes[4][TDIM];
  for (int idx = threadIdx.x; idx < TDIM * HID; idx += 256)
    wes[idx >> 7][idx & 127] = We[idx];
  for (int idx = threadIdx.x; idx < TDIM; idx += 256) { fr[idx] = freq[idx]; ph[idx] = phase[idx]; }
  __syncthreads();
  int wave = threadIdx.x >> 6, lane = threadIdx.x & 63;
  int c0 = lane * 2;
  int hh = lane >> 4;
  for (long e = (long)blockIdx.x * 4 + wave; e < nE; e += (long)gridDim.x * 4) {
    float dt = dts[e];
    tes[wave][lane] = __cosf(dt * fr[lane] + ph[lane]);
    if (lane < TDIM - 64) tes[wave][lane + 64] = __cosf(dt * fr[lane + 64] + ph[lane + 64]);
    asm volatile("s_waitcnt lgkmcnt(0)" ::: "memory");
    float e0 = 0.f, e1 = 0.f;
    #pragma unroll 4
    for (int t = 0; t < TDIM; ++t) {
      float tv = tes[wave][t];
      float2 wv = *(const float2*)&wes[t][c0];
      e0 += tv * wv.x;
      e1 += tv * wv.y;
    }
    int sv = src[e], dv = dst[e];
    float2 kv = *(const float2*)(k + (size_t)sv * HID + c0);
    float2 qv = *(const float2*)(q + (size_t)dv * HID + c0);
    float p = qv.x * (kv.x + e0) + qv.y * (kv.y + e1);
    p += __shfl_xor(p, 1);
    p += __shfl_xor(p, 2);
    p += __shfl_xor(p, 4);
    p += __shfl_xor(p, 8);
    if ((lane & 15) == 0) {
      float a = p * 0.17677669529663687f;  // 1/sqrt(32)
      alpha[e * 4 + hh] = a;
      atomicMaxF(&m[(size_t)dv * 4 + hh], a);
    }
  }
}

// pass 2: a = exp(alpha - m[dst]); s[dst] += a
__global__ void k_edge_exp(const int* __restrict__ dst, float* __restrict__ alpha,
                           const float* __restrict__ m, float* __restrict__ s, int nE) {
  long total = (long)nE * 4;
  for (long i = (long)blockIdx.x * 256 + threadIdx.x; i < total; i += (long)gridDim.x * 256) {
    long e = i >> 2; int hh = (int)(i & 3);
    int dv = dst[e];
    float a = __expf(alpha[i] - m[(size_t)dv * 4 + hh]);
    alpha[i] = a;
    atomicAdd(&s[(size_t)dv * 4 + hh], a);
  }
}

// pass 3: out[dst] += (a/s[dst]) * (v[src] + e)
__global__ __launch_bounds__(256) void k_edge_agg(
    const int* __restrict__ src, const int* __restrict__ dst,
    const float* __restrict__ dts,
    const float* __restrict__ freq, const float* __restrict__ phase,
    const float* __restrict__ We,
    const float* __restrict__ vbuf, const float* __restrict__ alpha,
    const float* __restrict__ s, float* __restrict__ out, int nE) {
  __shared__ float wes[TDIM][HID];
  __shared__ float fr[TDIM], ph[TDIM];
  __shared__ float tes[4][TDIM];
  for (int idx = threadIdx.x; idx < TDIM * HID; idx += 256)
    wes[idx >> 7][idx & 127] = We[idx];
  for (int idx = threadIdx.x; idx < TDIM; idx += 256) { fr[idx] = freq[idx]; ph[idx] = phase[idx]; }
  __syncthreads();
  int wave = threadIdx.x >> 6, lane = threadIdx.x & 63;
  int c0 = lane * 2;
  int hh = lane >> 4;
  for (long e = (long)blockIdx.x * 4 + wave; e < nE; e += (long)gridDim.x * 4) {
    float dt = dts[e];
    tes[wave][lane] = __cosf(dt * fr[lane] + ph[lane]);
    if (lane < TDIM - 64) tes[wave][lane + 64] = __cosf(dt * fr[lane + 64] + ph[lane + 64]);
    asm volatile("s_waitcnt lgkmcnt(0)" ::: "memory");
    float e0 = 0.f, e1 = 0.f;
    #pragma unroll 4
    for (int t = 0; t < TDIM; ++t) {
      float tv = tes[wave][t];
      float2 wv = *(const float2*)&wes[t][c0];
      e0 += tv * wv.x;
      e1 += tv * wv.y;
    }
    int sv = src[e], dv = dst[e];
    float w = alpha[e * 4 + hh] / (s[(size_t)dv * 4 + hh] + 1e-16f);
    float2 vv = *(const float2*)(vbuf + (size_t)sv * HID + c0);
    atomicAdd(&out[(size_t)dv * HID + c0], w * (vv.x + e0));
    atomicAdd(&out[(size_t)dv * HID + c0 + 1], w * (vv.y + e1));
  }
}

template <bool PRE_RELU>
__global__ void k_bn_reduce(const float* __restrict__ X, int n, int C, int shift,
                            float* __restrict__ sums) {
  int col = threadIdx.x & (C - 1);
  int rloc = threadIdx.x >> shift;
  int rpt = 256 >> shift;
  float s = 0.f, s2 = 0.f;
  for (long r = (long)blockIdx.x * rpt + rloc; r < n; r += (long)gridDim.x * rpt) {
    float v = X[r * C + col];
    if (PRE_RELU) v = v > 0.f ? v : 0.f;
    s += v; s2 += v * v;
  }
  __shared__ float ls[256], ls2[256];
  ls[threadIdx.x] = s; ls2[threadIdx.x] = s2;
  __syncthreads();
  if (rloc == 0) {
    for (int j = 1; j < rpt; ++j) { s += ls[j * C + col]; s2 += ls2[j * C + col]; }
    atomicAdd(&sums[col], s);
    atomicAdd(&sums[C + col], s2);
  }
}

template <bool PRE_RELU, bool POST_RELU>
__global__ void k_bn_apply(const float* __restrict__ X, int n, int C,
                           const float* __restrict__ sums,
                           const float* __restrict__ g, const float* __restrict__ b,
                           float* __restrict__ Y) {
  long total = (long)n * C;
  float inv_n = 1.f / (float)n;
  for (long i = (long)blockIdx.x * 256 + threadIdx.x; i < total; i += (long)gridDim.x * 256) {
    int col = (int)(i & (C - 1));
    float mean = sums[col] * inv_n;
    float var = sums[C + col] * inv_n - mean * mean;
    float v = X[i];
    if (PRE_RELU) v = v > 0.f ? v : 0.f;
    v = g[col] * (v - mean) * rsqrtf(var + 1e-5f) + b[col];
    if (POST_RELU) v = v > 0.f ? v : 0.f;
    Y[i] = v;
  }
}

// out[row] = z2[row] . W3 + b3, one wave per row
__global__ __launch_bounds__(256) void k_final(
    const float* __restrict__ z2, const float* __restrict__ W3,
    const float* __restrict__ b3, float* __restrict__ out, int n) {
  int wave = threadIdx.x >> 6, lane = threadIdx.x & 63;
  int row = blockIdx.x * 4 + wave;
  if (row >= n) return;
  float pv = z2[(size_t)row * 64 + lane] * W3[lane];
  pv += __shfl_xor(pv, 1);
  pv += __shfl_xor(pv, 2);
  pv += __shfl_xor(pv, 4);
  pv += __shfl_xor(pv, 8);
  pv += __shfl_xor(pv, 16);
  pv += __shfl_xor(pv, 32);
  if (lane == 0) out[row] = pv + b3[0];
}

extern "C" void kernel_launch(void* const* d_in, const int* in_sizes, int n_in,
                              void* d_out, int out_size, void* d_ws, size_t ws_size,
                              hipStream_t stream) {
  const float* x_all = (const float*)d_in[0];
  const int* ids = (const int*)d_in[1];
  const int* esrc = (const int*)d_in[2];
  const int* edst = (const int*)d_in[3];
  const float* dts = (const float*)d_in[4];
  const float* freq = (const float*)d_in[6];
  const float* phase = (const float*)d_in[7];
  const float* Wp = (const float*)d_in[8];
  const float* bp = (const float*)d_in[9];
  const float* Wq = (const float*)d_in[10];
  const float* bq = (const float*)d_in[11];
  const float* Wk = (const float*)d_in[12];
  const float* bk = (const float*)d_in[13];
  const float* Wv = (const float*)d_in[14];
  const float* bv = (const float*)d_in[15];
  const float* We = (const float*)d_in[16];
  const float* Wskip = (const float*)d_in[17];
  const float* bskip = (const float*)d_in[18];
  const float* bn_g = (const float*)d_in[19];
  const float* bn_b = (const float*)d_in[20];
  const float* W1 = (const float*)d_in[21];
  const float* b1 = (const float*)d_in[22];
  const float* g1 = (const float*)d_in[23];
  const float* be1 = (const float*)d_in[24];
  const float* W2 = (const float*)d_in[25];
  const float* b2 = (const float*)d_in[26];
  const float* g2 = (const float*)d_in[27];
  const float* be2 = (const float*)d_in[28];
  const float* W3 = (const float*)d_in[29];
  const float* b3 = (const float*)d_in[30];

  size_t n = (size_t)in_sizes[1];
  size_t nE = (size_t)in_sizes[2] / 2;
  int B = out_size;

  float* p = (float*)d_ws;
  float* h = p;     p += n * HID;
  float* qb = p;    p += n * HID;
  float* kb = p;    p += n * HID;
  float* vb = p;    p += n * HID;
  float* ob = p;    p += n * HID;
  float* alpha = p; p += nE * 4;
  float* mbuf = p;  p += n * 4;
  float* sbuf = p;  p += n * 4;
  float* sums = p;  p += 256;
  float* z1 = p;    p += (size_t)B * HID;
  float* z2 = p;    p += (size_t)B * 64;

  int gn8 = (int)((n + 7) / 8);
  k_in_gemm<<<gn8, 256, 0, stream>>>(x_all, ids, Wp, bp, h, (int)n);

  for (int i = 0; i < 2; ++i) {
    const int* src_i = esrc + i * nE;
    const int* dst_i = edst + i * nE;
    const float* dts_i = dts + i * nE;
    const float* We_i = We + (size_t)i * TDIM * HID;
    k_gemm128<<<gn8, 256, 0, stream>>>(h, Wq + (size_t)i * HID * HID, bq + i * HID, qb, (int)n);
    k_gemm128<<<gn8, 256, 0, stream>>>(h, Wk + (size_t)i * HID * HID, bk + i * HID, kb, (int)n);
    k_gemm128<<<gn8, 256, 0, stream>>>(h, Wv + (size_t)i * HID * HID, bv + i * HID, vb, (int)n);
    k_gemm128<<<gn8, 256, 0, stream>>>(h, Wskip + (size_t)i * HID * HID, bskip + i * HID, ob, (int)n);
    k_init_ms<<<(int)((n * 4 + 255) / 256), 256, 0, stream>>>(mbuf, sbuf, (int)(n * 4));
    k_edge_alpha<<<2048, 256, 0, stream>>>(src_i, dst_i, dts_i, freq, phase, We_i,
                                           qb, kb, alpha, mbuf, (int)nE);
    k_edge_exp<<<4096, 256, 0, stream>>>(dst_i, alpha, mbuf, sbuf, (int)nE);
    k_edge_agg<<<2048, 256, 0, stream>>>(src_i, dst_i, dts_i, freq, phase, We_i,
                                         vb, alpha, sbuf, ob, (int)nE);
    hipMemsetAsync(sums, 0, 2 * HID * sizeof(float), stream);
    k_bn_reduce<true><<<512, 256, 0, stream>>>(ob, (int)n, HID, 7, sums);
    k_bn_apply<true, false><<<4096, 256, 0, stream>>>(ob, (int)n, HID, sums,
                                                      bn_g + i * HID, bn_b + i * HID, h);
  }

  // MLP head on first B rows of h
  k_gemm128<<<(B + 7) / 8, 256, 0, stream>>>(h, W1, b1, z1, B);
  hipMemsetAsync(sums, 0, 2 * HID * sizeof(float), stream);
  k_bn_reduce<false><<<512, 256, 0, stream>>>(z1, B, HID, 7, sums);
  k_bn_apply<false, true><<<2048, 256, 0, stream>>>(z1, B, HID, sums, g1, be1, z1);
  k_gemm_64<<<(B + 15) / 16, 256, 0, stream>>>(z1, W2, b2, z2, B);
  hipMemsetAsync(sums, 0, 2 * 64 * sizeof(float), stream);
  k_bn_reduce<false><<<512, 256, 0, stream>>>(z2, B, 64, 6, sums);
  k_bn_apply<false, true><<<2048, 256, 0, stream>>>(z2, B, 64, sums, g2, be2, z2);
  k_final<<<(B + 3) / 4, 256, 0, stream>>>(z2, W3, b3, (float*)d_out, B);
}

// Round 2
// 2905.958 us; speedup vs baseline: 1.4028x; 1.4028x over previous
//
#include <hip/hip_runtime.h>
#include <hip/hip_bf16.h>
#include <math.h>

#define IN_DIM 172
#define HID 128
#define TDIM 100

typedef __attribute__((ext_vector_type(8))) short bf16x8;
typedef __attribute__((ext_vector_type(4))) float f32x4;

static __device__ __forceinline__ ushort f2b(float x) {
  unsigned u = __float_as_uint(x);
  u += 0x7FFFu + ((u >> 16) & 1u);
  return (ushort)(u >> 16);
}

__device__ inline void atomicMaxF(float* addr, float val) {
  int old = __float_as_int(*addr);
  while (__int_as_float(old) < val) {
    int assumed = old;
    old = atomicCAS((int*)addr, assumed, __float_as_int(val));
    if (old == assumed) break;
  }
}

// h = relu(x_all[ids] @ Wp + bp), 8 rows/block
__global__ __launch_bounds__(256) void k_in_gemm(
    const float* __restrict__ x_all, const int* __restrict__ ids,
    const float* __restrict__ Wp, const float* __restrict__ bp,
    float* __restrict__ h, int n) {
  __shared__ float xs[8][IN_DIM];
  int r0 = blockIdx.x * 8;
  for (int idx = threadIdx.x; idx < 8 * IN_DIM; idx += 256) {
    int r = idx / IN_DIM, c = idx - r * IN_DIM;
    int row = r0 + r;
    xs[r][c] = (row < n) ? x_all[(size_t)ids[row] * IN_DIM + c] : 0.f;
  }
  __syncthreads();
  int col = threadIdx.x & 127;
  int rg = threadIdx.x >> 7;
  float acc[4] = {0.f, 0.f, 0.f, 0.f};
  #pragma unroll 4
  for (int kk = 0; kk < IN_DIM; ++kk) {
    float w = Wp[kk * HID + col];
    #pragma unroll
    for (int j = 0; j < 4; ++j) acc[j] += xs[rg + 2 * j][kk] * w;
  }
  float bias = bp[col];
  #pragma unroll
  for (int j = 0; j < 4; ++j) {
    int row = r0 + rg + 2 * j;
    if (row < n) {
      float v = acc[j] + bias;
      h[(size_t)row * HID + col] = v > 0.f ? v : 0.f;
    }
  }
}

// Y = X @ W + b (X: n x 128, W: 128 x 128), 8 rows/block
__global__ __launch_bounds__(256) void k_gemm128(
    const float* __restrict__ X, const float* __restrict__ W,
    const float* __restrict__ b, float* __restrict__ Y, int n) {
  __shared__ float xs[8][HID];
  int r0 = blockIdx.x * 8;
  for (int idx = threadIdx.x; idx < 8 * HID; idx += 256) {
    int r = idx >> 7, c = idx & 127;
    int row = r0 + r;
    xs[r][c] = (row < n) ? X[(size_t)row * HID + c] : 0.f;
  }
  __syncthreads();
  int col = threadIdx.x & 127;
  int rg = threadIdx.x >> 7;
  float acc[4] = {0.f, 0.f, 0.f, 0.f};
  #pragma unroll 4
  for (int kk = 0; kk < HID; ++kk) {
    float w = W[kk * HID + col];
    #pragma unroll
    for (int j = 0; j < 4; ++j) acc[j] += xs[rg + 2 * j][kk] * w;
  }
  float bias = b[col];
  #pragma unroll
  for (int j = 0; j < 4; ++j) {
    int row = r0 + rg + 2 * j;
    if (row < n) Y[(size_t)row * HID + col] = acc[j] + bias;
  }
}

// Y = X @ W + b (X: n x 128, W: 128 x 64), 16 rows/block
__global__ __launch_bounds__(256) void k_gemm_64(
    const float* __restrict__ X, const float* __restrict__ W,
    const float* __restrict__ b, float* __restrict__ Y, int n) {
  __shared__ float xs[16][HID];
  int r0 = blockIdx.x * 16;
  for (int idx = threadIdx.x; idx < 16 * HID; idx += 256) {
    int r = idx >> 7, c = idx & 127;
    int row = r0 + r;
    xs[r][c] = (row < n) ? X[(size_t)row * HID + c] : 0.f;
  }
  __syncthreads();
  int col = threadIdx.x & 63;
  int rg = threadIdx.x >> 6;
  float acc[4] = {0.f, 0.f, 0.f, 0.f};
  #pragma unroll 4
  for (int kk = 0; kk < HID; ++kk) {
    float w = W[kk * 64 + col];
    #pragma unroll
    for (int j = 0; j < 4; ++j) acc[j] += xs[rg + 4 * j][kk] * w;
  }
  float bias = b[col];
  #pragma unroll
  for (int j = 0; j < 4; ++j) {
    int row = r0 + rg + 4 * j;
    if (row < n) Y[(size_t)row * 64 + col] = acc[j] + bias;
  }
}

__global__ void k_init_ms(float* __restrict__ m, float* __restrict__ s, int count) {
  int i = blockIdx.x * 256 + threadIdx.x;
  if (i < count) { m[i] = -INFINITY; s[i] = 0.f; }
}

// WeT[c][t] = bf16(We[t][c]), zero-padded t in [100,128)
__global__ void k_wet(const float* __restrict__ We, ushort* __restrict__ wet) {
  int i = blockIdx.x * 256 + threadIdx.x;
  if (i >= 128 * 128) return;
  int c = i >> 7, t = i & 127;
  wet[i] = (t < TDIM) ? f2b(We[t * HID + c]) : (ushort)0;
}

// e[E][128] = cos(dt*f+p) @ We via MFMA, bf16 out
__global__ __launch_bounds__(256) void k_te_mfma(
    const float* __restrict__ dts, const float* __restrict__ freq,
    const float* __restrict__ phase, const ushort* __restrict__ wet,
    ushort* __restrict__ eb, int nE) {
  __shared__ __align__(16) ushort te[64][136];
  __shared__ float dt_s[64];
  __shared__ float fr_s[128], ph_s[128];
  int tid = threadIdx.x;
  if (tid < 128) {
    fr_s[tid] = (tid < TDIM) ? freq[tid] : 0.f;
    ph_s[tid] = (tid < TDIM) ? phase[tid] : 0.f;
  }
  long e0 = (long)blockIdx.x << 6;
  if (tid < 64) dt_s[tid] = (e0 + tid < nE) ? dts[e0 + tid] : 0.f;
  __syncthreads();
  for (int i = tid; i < 64 * 128; i += 256) {
    int el = i >> 7, t = i & 127;
    float val = (t < TDIM) ? __cosf(dt_s[el] * fr_s[t] + ph_s[t]) : 0.f;
    te[el][t] = f2b(val);
  }
  __syncthreads();
  int wv = tid >> 6, l = tid & 63;
  int arow = wv * 16 + (l & 15);
  int kb0 = (l >> 4) * 8;
  bf16x8 a[4];
  #pragma unroll
  for (int kk = 0; kk < 4; ++kk)
    a[kk] = *(const bf16x8*)&te[arow][kk * 32 + kb0];
  #pragma unroll
  for (int nt = 0; nt < 8; ++nt) {
    int col = nt * 16 + (l & 15);
    const ushort* wcol = wet + (size_t)col * 128 + kb0;
    f32x4 acc = {0.f, 0.f, 0.f, 0.f};
    #pragma unroll
    for (int kk = 0; kk < 4; ++kk) {
      bf16x8 bfr = *(const bf16x8*)(wcol + kk * 32);
      acc = __builtin_amdgcn_mfma_f32_16x16x32_bf16(a[kk], bfr, acc, 0, 0, 0);
    }
    #pragma unroll
    for (int j = 0; j < 4; ++j) {
      long row = e0 + wv * 16 + (l >> 4) * 4 + j;
      if (row < nE) eb[row * 128 + col] = f2b(acc[j]);
    }
  }
}

// alpha[e][h] = q[dst].(k[src]+e) * 1/sqrt(32); atomicMax m
__global__ void k_alpha_v2(
    const int* __restrict__ src, const int* __restrict__ dst,
    const float* __restrict__ q, const float* __restrict__ k,
    const ushort* __restrict__ eb,
    float* __restrict__ alpha, float* __restrict__ m, int nE) {
  int wave = threadIdx.x >> 6, lane = threadIdx.x & 63;
  int c0 = lane * 2, hh = lane >> 4;
  for (long e = (long)blockIdx.x * 4 + wave; e < nE; e += (long)gridDim.x * 4) {
    int sv = src[e], dv = dst[e];
    float2 kv = *(const float2*)(k + (size_t)sv * HID + c0);
    float2 qv = *(const float2*)(q + (size_t)dv * HID + c0);
    unsigned ew = *(const unsigned*)(eb + (size_t)e * HID + c0);
    float ee0 = __uint_as_float(ew << 16);
    float ee1 = __uint_as_float(ew & 0xffff0000u);
    float pv = qv.x * (kv.x + ee0) + qv.y * (kv.y + ee1);
    pv += __shfl_xor(pv, 1);
    pv += __shfl_xor(pv, 2);
    pv += __shfl_xor(pv, 4);
    pv += __shfl_xor(pv, 8);
    if ((lane & 15) == 0) {
      float a = pv * 0.17677669529663687f;
      alpha[e * 4 + hh] = a;
      atomicMaxF(&m[(size_t)dv * 4 + hh], a);
    }
  }
}

// a = exp(alpha - m[dst]); s[dst] += a
__global__ void k_edge_exp(const int* __restrict__ dst, float* __restrict__ alpha,
                           const float* __restrict__ m, float* __restrict__ s, int nE) {
  long total = (long)nE * 4;
  for (long i = (long)blockIdx.x * 256 + threadIdx.x; i < total; i += (long)gridDim.x * 256) {
    long e = i >> 2; int hh = (int)(i & 3);
    int dv = dst[e];
    float a = __expf(alpha[i] - m[(size_t)dv * 4 + hh]);
    alpha[i] = a;
    atomicAdd(&s[(size_t)dv * 4 + hh], a);
  }
}

// out[dst] += (a/s[dst]) * (v[src] + e)
__global__ void k_agg_v2(
    const int* __restrict__ src, const int* __restrict__ dst,
    const ushort* __restrict__ eb, const float* __restrict__ vb,
    const float* __restrict__ alpha, const float* __restrict__ s,
    float* __restrict__ out, int nE) {
  int wave = threadIdx.x >> 6, lane = threadIdx.x & 63;
  int c0 = lane * 2, hh = lane >> 4;
  for (long e = (long)blockIdx.x * 4 + wave; e < nE; e += (long)gridDim.x * 4) {
    int sv = src[e], dv = dst[e];
    float a = alpha[e * 4 + hh];
    float sd = s[(size_t)dv * 4 + hh];
    float w = a / (sd + 1e-16f);
    float2 vv = *(const float2*)(vb + (size_t)sv * HID + c0);
    unsigned ew = *(const unsigned*)(eb + (size_t)e * HID + c0);
    float ee0 = __uint_as_float(ew << 16);
    float ee1 = __uint_as_float(ew & 0xffff0000u);
    atomicAdd(&out[(size_t)dv * HID + c0], w * (vv.x + ee0));
    atomicAdd(&out[(size_t)dv * HID + c0 + 1], w * (vv.y + ee1));
  }
}

template <bool PRE_RELU>
__global__ void k_bn_reduce(const float* __restrict__ X, int n, int C, int shift,
                            float* __restrict__ sums) {
  int col = threadIdx.x & (C - 1);
  int rloc = threadIdx.x >> shift;
  int rpt = 256 >> shift;
  float s = 0.f, s2 = 0.f;
  for (long r = (long)blockIdx.x * rpt + rloc; r < n; r += (long)gridDim.x * rpt) {
    float v = X[r * C + col];
    if (PRE_RELU) v = v > 0.f ? v : 0.f;
    s += v; s2 += v * v;
  }
  __shared__ float ls[256], ls2[256];
  ls[threadIdx.x] = s; ls2[threadIdx.x] = s2;
  __syncthreads();
  if (rloc == 0) {
    for (int j = 1; j < rpt; ++j) { s += ls[j * C + col]; s2 += ls2[j * C + col]; }
    atomicAdd(&sums[col], s);
    atomicAdd(&sums[C + col], s2);
  }
}

template <bool PRE_RELU, bool POST_RELU>
__global__ void k_bn_apply(const float* __restrict__ X, int n, int C,
                           const float* __restrict__ sums,
                           const float* __restrict__ g, const float* __restrict__ b,
                           float* __restrict__ Y) {
  long total = (long)n * C;
  float inv_n = 1.f / (float)n;
  for (long i = (long)blockIdx.x * 256 + threadIdx.x; i < total; i += (long)gridDim.x * 256) {
    int col = (int)(i & (C - 1));
    float mean = sums[col] * inv_n;
    float var = sums[C + col] * inv_n - mean * mean;
    float v = X[i];
    if (PRE_RELU) v = v > 0.f ? v : 0.f;
    v = g[col] * (v - mean) * rsqrtf(var + 1e-5f) + b[col];
    if (POST_RELU) v = v > 0.f ? v : 0.f;
    Y[i] = v;
  }
}

__global__ __launch_bounds__(256) void k_final(
    const float* __restrict__ z2, const float* __restrict__ W3,
    const float* __restrict__ b3, float* __restrict__ out, int n) {
  int wave = threadIdx.x >> 6, lane = threadIdx.x & 63;
  int row = blockIdx.x * 4 + wave;
  if (row >= n) return;
  float pv = z2[(size_t)row * 64 + lane] * W3[lane];
  pv += __shfl_xor(pv, 1);
  pv += __shfl_xor(pv, 2);
  pv += __shfl_xor(pv, 4);
  pv += __shfl_xor(pv, 8);
  pv += __shfl_xor(pv, 16);
  pv += __shfl_xor(pv, 32);
  if (lane == 0) out[row] = pv + b3[0];
}

extern "C" void kernel_launch(void* const* d_in, const int* in_sizes, int n_in,
                              void* d_out, int out_size, void* d_ws, size_t ws_size,
                              hipStream_t stream) {
  const float* x_all = (const float*)d_in[0];
  const int* ids = (const int*)d_in[1];
  const int* esrc = (const int*)d_in[2];
  const int* edst = (const int*)d_in[3];
  const float* dts = (const float*)d_in[4];
  const float* freq = (const float*)d_in[6];
  const float* phase = (const float*)d_in[7];
  const float* Wp = (const float*)d_in[8];
  const float* bp = (const float*)d_in[9];
  const float* Wq = (const float*)d_in[10];
  const float* bq = (const float*)d_in[11];
  const float* Wk = (const float*)d_in[12];
  const float* bk = (const float*)d_in[13];
  const float* Wv = (const float*)d_in[14];
  const float* bv = (const float*)d_in[15];
  const float* We = (const float*)d_in[16];
  const float* Wskip = (const float*)d_in[17];
  const float* bskip = (const float*)d_in[18];
  const float* bn_g = (const float*)d_in[19];
  const float* bn_b = (const float*)d_in[20];
  const float* W1 = (const float*)d_in[21];
  const float* b1 = (const float*)d_in[22];
  const float* g1 = (const float*)d_in[23];
  const float* be1 = (const float*)d_in[24];
  const float* W2 = (const float*)d_in[25];
  const float* b2 = (const float*)d_in[26];
  const float* g2 = (const float*)d_in[27];
  const float* be2 = (const float*)d_in[28];
  const float* W3 = (const float*)d_in[29];
  const float* b3 = (const float*)d_in[30];

  size_t n = (size_t)in_sizes[1];
  size_t nE = (size_t)in_sizes[2] / 2;
  int B = out_size;

  char* pc = (char*)d_ws;
  auto alloc = [&](size_t bytes) { char* r = pc; pc += (bytes + 255) & ~(size_t)255; return r; };
  float* h    = (float*)alloc(n * HID * 4);
  float* bufA = (float*)alloc(n * HID * 4);   // qb, then vb
  float* bufB = (float*)alloc(n * HID * 4);   // kb, then ob
  ushort* eb  = (ushort*)alloc(nE * HID * 2);
  float* alpha = (float*)alloc(nE * 4 * 4);
  float* mbuf = (float*)alloc(n * 4 * 4);
  float* sbuf = (float*)alloc(n * 4 * 4);
  float* sums = (float*)alloc(256 * 4);
  ushort* wet = (ushort*)alloc(128 * 128 * 2);
  float* z1   = (float*)alloc((size_t)B * HID * 4);
  float* z2   = (float*)alloc((size_t)B * 64 * 4);

  int gn8 = (int)((n + 7) / 8);
  int eblk = (int)((nE + 63) / 64);
  k_in_gemm<<<gn8, 256, 0, stream>>>(x_all, ids, Wp, bp, h, (int)n);

  for (int i = 0; i < 2; ++i) {
    const int* src_i = esrc + i * nE;
    const int* dst_i = edst + i * nE;
    const float* dts_i = dts + i * nE;
    const float* We_i = We + (size_t)i * TDIM * HID;
    // q, k projections
    k_gemm128<<<gn8, 256, 0, stream>>>(h, Wq + (size_t)i * HID * HID, bq + i * HID, bufA, (int)n);
    k_gemm128<<<gn8, 256, 0, stream>>>(h, Wk + (size_t)i * HID * HID, bk + i * HID, bufB, (int)n);
    // e = cos(dt*f+p) @ We  (bf16, MFMA)
    k_wet<<<64, 256, 0, stream>>>(We_i, wet);
    k_te_mfma<<<eblk, 256, 0, stream>>>(dts_i, freq, phase, wet, eb, (int)nE);
    // attention scores
    k_init_ms<<<(int)((n * 4 + 255) / 256), 256, 0, stream>>>(mbuf, sbuf, (int)(n * 4));
    k_alpha_v2<<<4096, 256, 0, stream>>>(src_i, dst_i, bufA, bufB, eb, alpha, mbuf, (int)nE);
    k_edge_exp<<<4096, 256, 0, stream>>>(dst_i, alpha, mbuf, sbuf, (int)nE);
    // v, skip projections (reuse buffers; q/k dead now)
    k_gemm128<<<gn8, 256, 0, stream>>>(h, Wv + (size_t)i * HID * HID, bv + i * HID, bufA, (int)n);
    k_gemm128<<<gn8, 256, 0, stream>>>(h, Wskip + (size_t)i * HID * HID, bskip + i * HID, bufB, (int)n);
    // aggregate into skip output
    k_agg_v2<<<4096, 256, 0, stream>>>(src_i, dst_i, eb, bufA, alpha, sbuf, bufB, (int)nE);
    // bn(relu(out)) -> h
    hipMemsetAsync(sums, 0, 2 * HID * sizeof(float), stream);
    k_bn_reduce<true><<<512, 256, 0, stream>>>(bufB, (int)n, HID, 7, sums);
    k_bn_apply<true, false><<<4096, 256, 0, stream>>>(bufB, (int)n, HID, sums,
                                                      bn_g + i * HID, bn_b + i * HID, h);
  }

  // MLP head on first B rows of h
  k_gemm128<<<(B + 7) / 8, 256, 0, stream>>>(h, W1, b1, z1, B);
  hipMemsetAsync(sums, 0, 2 * HID * sizeof(float), stream);
  k_bn_reduce<false><<<512, 256, 0, stream>>>(z1, B, HID, 7, sums);
  k_bn_apply<false, true><<<2048, 256, 0, stream>>>(z1, B, HID, sums, g1, be1, z1);
  k_gemm_64<<<(B + 15) / 16, 256, 0, stream>>>(z1, W2, b2, z2, B);
  hipMemsetAsync(sums, 0, 2 * 64 * sizeof(float), stream);
  k_bn_reduce<false><<<512, 256, 0, stream>>>(z2, B, 64, 6, sums);
  k_bn_apply<false, true><<<2048, 256, 0, stream>>>(z2, B, 64, sums, g2, be2, z2);
  k_final<<<(B + 3) / 4, 256, 0, stream>>>(z2, W3, b3, (float*)d_out, B);
}

// Round 3
// 1468.396 us; speedup vs baseline: 2.7761x; 1.9790x over previous
//
#include <hip/hip_runtime.h>
#include <hip/hip_bf16.h>
#include <math.h>

#define IN_DIM 172
#define HID 128
#define TDIM 100

typedef __attribute__((ext_vector_type(8))) short bf16x8;
typedef __attribute__((ext_vector_type(4))) float f32x4;

static __device__ __forceinline__ ushort f2b(float x) {
  unsigned u = __float_as_uint(x);
  u += 0x7FFFu + ((u >> 16) & 1u);
  return (ushort)(u >> 16);
}
static __device__ __forceinline__ float blo(unsigned w) { return __uint_as_float(w << 16); }
static __device__ __forceinline__ float bhi(unsigned w) { return __uint_as_float(w & 0xffff0000u); }

// h = relu(x_all[ids] @ Wp + bp) -> bf16, 8 rows/block
__global__ __launch_bounds__(256) void k_in_gemm(
    const float* __restrict__ x_all, const int* __restrict__ ids,
    const float* __restrict__ Wp, const float* __restrict__ bp,
    ushort* __restrict__ h, int n) {
  __shared__ float xs[8][IN_DIM];
  int r0 = blockIdx.x * 8;
  for (int idx = threadIdx.x; idx < 8 * IN_DIM; idx += 256) {
    int r = idx / IN_DIM, c = idx - r * IN_DIM;
    int row = r0 + r;
    xs[r][c] = (row < n) ? x_all[(size_t)ids[row] * IN_DIM + c] : 0.f;
  }
  __syncthreads();
  int col = threadIdx.x & 127;
  int rg = threadIdx.x >> 7;
  float acc[4] = {0.f, 0.f, 0.f, 0.f};
  #pragma unroll 4
  for (int kk = 0; kk < IN_DIM; ++kk) {
    float w = Wp[kk * HID + col];
    #pragma unroll
    for (int j = 0; j < 4; ++j) acc[j] += xs[rg + 2 * j][kk] * w;
  }
  float bias = bp[col];
  #pragma unroll
  for (int j = 0; j < 4; ++j) {
    int row = r0 + rg + 2 * j;
    if (row < n) {
      float v = acc[j] + bias;
      h[(size_t)row * HID + col] = f2b(v > 0.f ? v : 0.f);
    }
  }
}

// pack WqT|WkT|WvT|WskipT -> wallT[512][128] bf16, biases -> ball[512]
__global__ void k_wprep(const float* __restrict__ Wq, const float* __restrict__ Wk,
                        const float* __restrict__ Wv, const float* __restrict__ Ws,
                        const float* __restrict__ bq, const float* __restrict__ bk,
                        const float* __restrict__ bv, const float* __restrict__ bs,
                        ushort* __restrict__ wallT, float* __restrict__ ball) {
  int i = blockIdx.x * 256 + threadIdx.x;
  if (i >= 512 * 128) return;
  int col = i >> 7, k = i & 127;
  int m = col >> 7, c = col & 127;
  const float* W = (m == 0) ? Wq : (m == 1) ? Wk : (m == 2) ? Wv : Ws;
  wallT[i] = f2b(W[k * HID + c]);
  if (k == 0) {
    const float* bb = (m == 0) ? bq : (m == 1) ? bk : (m == 2) ? bv : bs;
    ball[col] = bb[c];
  }
}

// W1T[c][k] = bf16(W1[k][c])
__global__ void k_wt128(const float* __restrict__ W, ushort* __restrict__ wt) {
  int i = blockIdx.x * 256 + threadIdx.x;
  if (i >= 128 * 128) return;
  int c = i >> 7, k = i & 127;
  wt[i] = f2b(W[k * HID + c]);
}

// fused q/k/v/skip: y = h @ [Wq|Wk|Wv|Ws] + b; q,k,v bf16; skip f32 -> ob
__global__ __launch_bounds__(256) void k_qkvs(
    const ushort* __restrict__ h, const ushort* __restrict__ wallT,
    const float* __restrict__ ball,
    ushort* __restrict__ qb, ushort* __restrict__ kbuf, ushort* __restrict__ vb,
    float* __restrict__ ob, int n) {
  __shared__ __align__(16) ushort hs[64][136];
  int tid = threadIdx.x;
  long r0 = (long)blockIdx.x * 64;
  bf16x8 zv = {0, 0, 0, 0, 0, 0, 0, 0};
  for (int i = tid; i < 64 * 16; i += 256) {
    int r = i >> 4, cseg = i & 15;
    long row = r0 + r;
    bf16x8 v = (row < n) ? *(const bf16x8*)&h[row * HID + cseg * 8] : zv;
    *(bf16x8*)&hs[r][cseg * 8] = v;
  }
  __syncthreads();
  int wv = tid >> 6, l = tid & 63;
  int arow = wv * 16 + (l & 15);
  int kb0 = (l >> 4) * 8;
  bf16x8 a[4];
  #pragma unroll
  for (int kk = 0; kk < 4; ++kk) a[kk] = *(const bf16x8*)&hs[arow][kk * 32 + kb0];
  #pragma unroll 4
  for (int nt = 0; nt < 32; ++nt) {
    int col = nt * 16 + (l & 15);
    const ushort* wcol = wallT + (size_t)col * 128 + kb0;
    f32x4 acc = {0.f, 0.f, 0.f, 0.f};
    #pragma unroll
    for (int kk = 0; kk < 4; ++kk) {
      bf16x8 bfr = *(const bf16x8*)(wcol + kk * 32);
      acc = __builtin_amdgcn_mfma_f32_16x16x32_bf16(a[kk], bfr, acc, 0, 0, 0);
    }
    float bias = ball[col];
    int m = col >> 7, c = col & 127;
    #pragma unroll
    for (int j = 0; j < 4; ++j) {
      long row = r0 + wv * 16 + (l >> 4) * 4 + j;
      if (row < n) {
        float y = acc[j] + bias;
        if (m == 3) ob[row * HID + c] = y;
        else {
          ushort* db = (m == 0) ? qb : (m == 1) ? kbuf : vb;
          db[row * HID + c] = f2b(y);
        }
      }
    }
  }
}

// y = X(bf16) @ WT + b -> f32, 64 rows/block
__global__ __launch_bounds__(256) void k_mfma128(
    const ushort* __restrict__ X, const ushort* __restrict__ WT,
    const float* __restrict__ bias, float* __restrict__ Y, int n) {
  __shared__ __align__(16) ushort hs[64][136];
  int tid = threadIdx.x;
  long r0 = (long)blockIdx.x * 64;
  bf16x8 zv = {0, 0, 0, 0, 0, 0, 0, 0};
  for (int i = tid; i < 64 * 16; i += 256) {
    int r = i >> 4, cseg = i & 15;
    long row = r0 + r;
    bf16x8 v = (row < n) ? *(const bf16x8*)&X[row * HID + cseg * 8] : zv;
    *(bf16x8*)&hs[r][cseg * 8] = v;
  }
  __syncthreads();
  int wv = tid >> 6, l = tid & 63;
  int arow = wv * 16 + (l & 15);
  int kb0 = (l >> 4) * 8;
  bf16x8 a[4];
  #pragma unroll
  for (int kk = 0; kk < 4; ++kk) a[kk] = *(const bf16x8*)&hs[arow][kk * 32 + kb0];
  #pragma unroll
  for (int nt = 0; nt < 8; ++nt) {
    int col = nt * 16 + (l & 15);
    const ushort* wcol = WT + (size_t)col * 128 + kb0;
    f32x4 acc = {0.f, 0.f, 0.f, 0.f};
    #pragma unroll
    for (int kk = 0; kk < 4; ++kk) {
      bf16x8 bfr = *(const bf16x8*)(wcol + kk * 32);
      acc = __builtin_amdgcn_mfma_f32_16x16x32_bf16(a[kk], bfr, acc, 0, 0, 0);
    }
    float bs = bias[col];
    #pragma unroll
    for (int j = 0; j < 4; ++j) {
      long row = r0 + wv * 16 + (l >> 4) * 4 + j;
      if (row < n) Y[row * HID + col] = acc[j] + bs;
    }
  }
}

// ---- counting sort by dst ----
__global__ void k_hist(const int* __restrict__ dst, int* __restrict__ counts, int nE) {
  int e = blockIdx.x * 256 + threadIdx.x;
  if (e < nE) atomicAdd(&counts[dst[e]], 1);
}

__global__ void k_scan_chunk(const int* __restrict__ counts, int* __restrict__ offs,
                             int* __restrict__ chunkSums, int n) {
  __shared__ int ls[256];
  int t = threadIdx.x;
  int base = blockIdx.x * 1024 + t * 4;
  int v[4];
  #pragma unroll
  for (int j = 0; j < 4; ++j) v[j] = (base + j < n) ? counts[base + j] : 0;
  ls[t] = v[0] + v[1] + v[2] + v[3];
  __syncthreads();
  for (int off = 1; off < 256; off <<= 1) {
    int x = (t >= off) ? ls[t - off] : 0;
    __syncthreads();
    ls[t] += x;
    __syncthreads();
  }
  int run = (t == 0) ? 0 : ls[t - 1];
  if (t == 255) chunkSums[blockIdx.x] = ls[255];
  #pragma unroll
  for (int j = 0; j < 4; ++j) {
    if (base + j < n) offs[base + j] = run;
    run += v[j];
  }
}

__global__ void k_scan_tops(int* __restrict__ chunkSums, int nchunks) {
  __shared__ int ls[256];
  int t = threadIdx.x;
  ls[t] = (t < nchunks) ? chunkSums[t] : 0;
  __syncthreads();
  for (int off = 1; off < 256; off <<= 1) {
    int x = (t >= off) ? ls[t - off] : 0;
    __syncthreads();
    ls[t] += x;
    __syncthreads();
  }
  int excl = (t == 0) ? 0 : ls[t - 1];
  if (t < nchunks) chunkSums[t] = excl;
}

__global__ void k_scan_add(int* __restrict__ offs, const int* __restrict__ chunkSums,
                           int n, int nE) {
  int i = blockIdx.x * 256 + threadIdx.x;
  if (i < n) offs[i] += chunkSums[i >> 10];
  if (i == 0) offs[n] = nE;
}

__global__ void k_scatter(const int* __restrict__ src, const int* __restrict__ dst,
                          const float* __restrict__ dts, const int* __restrict__ offs,
                          int* __restrict__ cursor, int* __restrict__ src_s,
                          float* __restrict__ dts_s, int nE) {
  int e = blockIdx.x * 256 + threadIdx.x;
  if (e >= nE) return;
  int d = dst[e];
  int pos = offs[d] + atomicAdd(&cursor[d], 1);
  src_s[pos] = src[e];
  dts_s[pos] = dts[e];
}

// WeT[c][t] = bf16(We[t][c]), zero-padded t in [100,128)
__global__ void k_wet(const float* __restrict__ We, ushort* __restrict__ wet) {
  int i = blockIdx.x * 256 + threadIdx.x;
  if (i >= 128 * 128) return;
  int c = i >> 7, t = i & 127;
  wet[i] = (t < TDIM) ? f2b(We[t * HID + c]) : (ushort)0;
}

// e[E][128] = cos(dt*f+p) @ We via MFMA, bf16 out (sorted dts)
__global__ __launch_bounds__(256) void k_te_mfma(
    const float* __restrict__ dts, const float* __restrict__ freq,
    const float* __restrict__ phase, const ushort* __restrict__ wet,
    ushort* __restrict__ eb, int nE) {
  __shared__ __align__(16) ushort te[64][136];
  __shared__ float dt_s[64];
  __shared__ float fr_s[128], ph_s[128];
  int tid = threadIdx.x;
  if (tid < 128) {
    fr_s[tid] = (tid < TDIM) ? freq[tid] : 0.f;
    ph_s[tid] = (tid < TDIM) ? phase[tid] : 0.f;
  }
  long e0 = (long)blockIdx.x << 6;
  if (tid < 64) dt_s[tid] = (e0 + tid < nE) ? dts[e0 + tid] : 0.f;
  __syncthreads();
  for (int i = tid; i < 64 * 128; i += 256) {
    int el = i >> 7, t = i & 127;
    float val = (t < TDIM) ? __cosf(dt_s[el] * fr_s[t] + ph_s[t]) : 0.f;
    te[el][t] = f2b(val);
  }
  __syncthreads();
  int wv = tid >> 6, l = tid & 63;
  int arow = wv * 16 + (l & 15);
  int kb0 = (l >> 4) * 8;
  bf16x8 a[4];
  #pragma unroll
  for (int kk = 0; kk < 4; ++kk) a[kk] = *(const bf16x8*)&te[arow][kk * 32 + kb0];
  #pragma unroll
  for (int nt = 0; nt < 8; ++nt) {
    int col = nt * 16 + (l & 15);
    const ushort* wcol = wet + (size_t)col * 128 + kb0;
    f32x4 acc = {0.f, 0.f, 0.f, 0.f};
    #pragma unroll
    for (int kk = 0; kk < 4; ++kk) {
      bf16x8 bfr = *(const bf16x8*)(wcol + kk * 32);
      acc = __builtin_amdgcn_mfma_f32_16x16x32_bf16(a[kk], bfr, acc, 0, 0, 0);
    }
    #pragma unroll
    for (int j = 0; j < 4; ++j) {
      long row = e0 + wv * 16 + (l >> 4) * 4 + j;
      if (row < nE) eb[row * 128 + col] = f2b(acc[j]);
    }
  }
}

// fused attention: one wave per dst, online softmax + weighted V accumulation
__global__ void k_attn(const int* __restrict__ offs, const int* __restrict__ src_s,
                       const ushort* __restrict__ eb, const ushort* __restrict__ qb,
                       const ushort* __restrict__ kb, const ushort* __restrict__ vb,
                       float* __restrict__ ob, int n) {
  int d = (blockIdx.x * 256 + threadIdx.x) >> 6;
  if (d >= n) return;
  int lane = threadIdx.x & 63;
  int c0 = lane * 2;
  int beg = offs[d], end = offs[d + 1];
  if (beg == end) return;
  unsigned qw = *(const unsigned*)(qb + (size_t)d * HID + c0);
  float q0 = blo(qw), q1 = bhi(qw);
  float m = -INFINITY, s = 0.f, acc0 = 0.f, acc1 = 0.f;
  for (int pos = beg; pos < end; ++pos) {
    int sv = src_s[pos];
    unsigned kw = *(const unsigned*)(kb + (size_t)sv * HID + c0);
    unsigned vw = *(const unsigned*)(vb + (size_t)sv * HID + c0);
    unsigned ew = *(const unsigned*)(eb + (size_t)pos * HID + c0);
    float e0 = blo(ew), e1 = bhi(ew);
    float p = q0 * (blo(kw) + e0) + q1 * (bhi(kw) + e1);
    p += __shfl_xor(p, 1);
    p += __shfl_xor(p, 2);
    p += __shfl_xor(p, 4);
    p += __shfl_xor(p, 8);
    float a = p * 0.17677669529663687f;  // 1/sqrt(32)
    float nm = fmaxf(m, a);
    float sc = __expf(m - nm);
    float pe = __expf(a - nm);
    s = s * sc + pe;
    acc0 = acc0 * sc + pe * (blo(vw) + e0);
    acc1 = acc1 * sc + pe * (bhi(vw) + e1);
    m = nm;
  }
  float inv = 1.f / (s + 1e-16f);
  float* orow = ob + (size_t)d * HID + c0;
  orow[0] += acc0 * inv;
  orow[1] += acc1 * inv;
}

template <bool PRE_RELU>
__global__ void k_bn_reduce(const float* __restrict__ X, int n, int C, int shift,
                            float* __restrict__ sums) {
  int col = threadIdx.x & (C - 1);
  int rloc = threadIdx.x >> shift;
  int rpt = 256 >> shift;
  float s = 0.f, s2 = 0.f;
  for (long r = (long)blockIdx.x * rpt + rloc; r < n; r += (long)gridDim.x * rpt) {
    float v = X[r * C + col];
    if (PRE_RELU) v = v > 0.f ? v : 0.f;
    s += v; s2 += v * v;
  }
  __shared__ float ls[256], ls2[256];
  ls[threadIdx.x] = s; ls2[threadIdx.x] = s2;
  __syncthreads();
  if (rloc == 0) {
    for (int j = 1; j < rpt; ++j) { s += ls[j * C + col]; s2 += ls2[j * C + col]; }
    atomicAdd(&sums[col], s);
    atomicAdd(&sums[C + col], s2);
  }
}

template <bool PRE_RELU, bool POST_RELU, bool BF16OUT>
__global__ void k_bn_apply(const float* __restrict__ X, int n, int C,
                           const float* __restrict__ sums,
                           const float* __restrict__ g, const float* __restrict__ b,
                           void* __restrict__ Yv) {
  long total = (long)n * C;
  float inv_n = 1.f / (float)n;
  for (long i = (long)blockIdx.x * 256 + threadIdx.x; i < total; i += (long)gridDim.x * 256) {
    int col = (int)(i & (C - 1));
    float mean = sums[col] * inv_n;
    float var = sums[C + col] * inv_n - mean * mean;
    float v = X[i];
    if (PRE_RELU) v = v > 0.f ? v : 0.f;
    v = g[col] * (v - mean) * rsqrtf(var + 1e-5f) + b[col];
    if (POST_RELU) v = v > 0.f ? v : 0.f;
    if (BF16OUT) ((ushort*)Yv)[i] = f2b(v);
    else ((float*)Yv)[i] = v;
  }
}

// Y = X @ W + b (X: n x 128 f32, W: 128 x 64), 16 rows/block
__global__ __launch_bounds__(256) void k_gemm_64(
    const float* __restrict__ X, const float* __restrict__ W,
    const float* __restrict__ b, float* __restrict__ Y, int n) {
  __shared__ float xs[16][HID];
  int r0 = blockIdx.x * 16;
  for (int idx = threadIdx.x; idx < 16 * HID; idx += 256) {
    int r = idx >> 7, c = idx & 127;
    int row = r0 + r;
    xs[r][c] = (row < n) ? X[(size_t)row * HID + c] : 0.f;
  }
  __syncthreads();
  int col = threadIdx.x & 63;
  int rg = threadIdx.x >> 6;
  float acc[4] = {0.f, 0.f, 0.f, 0.f};
  #pragma unroll 4
  for (int kk = 0; kk < HID; ++kk) {
    float w = W[kk * 64 + col];
    #pragma unroll
    for (int j = 0; j < 4; ++j) acc[j] += xs[rg + 4 * j][kk] * w;
  }
  float bias = b[col];
  #pragma unroll
  for (int j = 0; j < 4; ++j) {
    int row = r0 + rg + 4 * j;
    if (row < n) Y[(size_t)row * 64 + col] = acc[j] + bias;
  }
}

__global__ __launch_bounds__(256) void k_final(
    const float* __restrict__ z2, const float* __restrict__ W3,
    const float* __restrict__ b3, float* __restrict__ out, int n) {
  int wave = threadIdx.x >> 6, lane = threadIdx.x & 63;
  int row = blockIdx.x * 4 + wave;
  if (row >= n) return;
  float pv = z2[(size_t)row * 64 + lane] * W3[lane];
  pv += __shfl_xor(pv, 1);
  pv += __shfl_xor(pv, 2);
  pv += __shfl_xor(pv, 4);
  pv += __shfl_xor(pv, 8);
  pv += __shfl_xor(pv, 16);
  pv += __shfl_xor(pv, 32);
  if (lane == 0) out[row] = pv + b3[0];
}

extern "C" void kernel_launch(void* const* d_in, const int* in_sizes, int n_in,
                              void* d_out, int out_size, void* d_ws, size_t ws_size,
                              hipStream_t stream) {
  const float* x_all = (const float*)d_in[0];
  const int* ids = (const int*)d_in[1];
  const int* esrc = (const int*)d_in[2];
  const int* edst = (const int*)d_in[3];
  const float* dts = (const float*)d_in[4];
  const float* freq = (const float*)d_in[6];
  const float* phase = (const float*)d_in[7];
  const float* Wp = (const float*)d_in[8];
  const float* bp = (const float*)d_in[9];
  const float* Wq = (const float*)d_in[10];
  const float* bq = (const float*)d_in[11];
  const float* Wk = (const float*)d_in[12];
  const float* bk = (const float*)d_in[13];
  const float* Wv = (const float*)d_in[14];
  const float* bv = (const float*)d_in[15];
  const float* We = (const float*)d_in[16];
  const float* Wskip = (const float*)d_in[17];
  const float* bskip = (const float*)d_in[18];
  const float* bn_g = (const float*)d_in[19];
  const float* bn_b = (const float*)d_in[20];
  const float* W1 = (const float*)d_in[21];
  const float* b1 = (const float*)d_in[22];
  const float* g1 = (const float*)d_in[23];
  const float* be1 = (const float*)d_in[24];
  const float* W2 = (const float*)d_in[25];
  const float* b2 = (const float*)d_in[26];
  const float* g2 = (const float*)d_in[27];
  const float* be2 = (const float*)d_in[28];
  const float* W3 = (const float*)d_in[29];
  const float* b3 = (const float*)d_in[30];

  size_t n = (size_t)in_sizes[1];
  size_t nE = (size_t)in_sizes[2] / 2;
  int B = out_size;

  char* pc = (char*)d_ws;
  auto alloc = [&](size_t bytes) { char* r = pc; pc += (bytes + 255) & ~(size_t)255; return r; };
  ushort* h    = (ushort*)alloc(n * HID * 2);
  ushort* qb   = (ushort*)alloc(n * HID * 2);
  ushort* kb   = (ushort*)alloc(n * HID * 2);
  ushort* vb   = (ushort*)alloc(n * HID * 2);
  float*  ob   = (float*)alloc(n * HID * 4);
  ushort* eb   = (ushort*)alloc(nE * HID * 2);
  int* src_s   = (int*)alloc(nE * 4);
  float* dts_s = (float*)alloc(nE * 4);
  int* counts  = (int*)alloc(n * 4);
  int* cursor  = (int*)alloc(n * 4);
  int* offs    = (int*)alloc((n + 1) * 4);
  int* chunkS  = (int*)alloc(256 * 4);
  ushort* wallT = (ushort*)alloc(512 * 128 * 2);
  float* ball  = (float*)alloc(512 * 4);
  ushort* wet  = (ushort*)alloc(128 * 128 * 2);
  ushort* w1t  = (ushort*)alloc(128 * 128 * 2);
  float* sums  = (float*)alloc(256 * 4);
  float* z1    = (float*)alloc((size_t)B * HID * 4);
  float* z2    = (float*)alloc((size_t)B * 64 * 4);

  int gn8 = (int)((n + 7) / 8);
  int gn64 = (int)((n + 63) / 64);
  int ge256 = (int)((nE + 255) / 256);
  int eblk = (int)((nE + 63) / 64);
  int nchunks = (int)((n + 1023) / 1024);

  k_in_gemm<<<gn8, 256, 0, stream>>>(x_all, ids, Wp, bp, h, (int)n);

  for (int i = 0; i < 2; ++i) {
    const int* src_i = esrc + i * nE;
    const int* dst_i = edst + i * nE;
    const float* dts_i = dts + i * nE;
    const float* We_i = We + (size_t)i * TDIM * HID;

    k_wprep<<<256, 256, 0, stream>>>(Wq + (size_t)i * HID * HID, Wk + (size_t)i * HID * HID,
                                     Wv + (size_t)i * HID * HID, Wskip + (size_t)i * HID * HID,
                                     bq + i * HID, bk + i * HID, bv + i * HID, bskip + i * HID,
                                     wallT, ball);
    k_qkvs<<<gn64, 256, 0, stream>>>(h, wallT, ball, qb, kb, vb, ob, (int)n);

    // counting sort by dst
    hipMemsetAsync(counts, 0, n * 4, stream);
    hipMemsetAsync(cursor, 0, n * 4, stream);
    k_hist<<<ge256, 256, 0, stream>>>(dst_i, counts, (int)nE);
    k_scan_chunk<<<nchunks, 256, 0, stream>>>(counts, offs, chunkS, (int)n);
    k_scan_tops<<<1, 256, 0, stream>>>(chunkS, nchunks);
    k_scan_add<<<(int)((n + 255) / 256), 256, 0, stream>>>(offs, chunkS, (int)n, (int)nE);
    k_scatter<<<ge256, 256, 0, stream>>>(src_i, dst_i, dts_i, offs, cursor, src_s, dts_s, (int)nE);

    // e = cos(dt f + p) @ We, in sorted order
    k_wet<<<64, 256, 0, stream>>>(We_i, wet);
    k_te_mfma<<<eblk, 256, 0, stream>>>(dts_s, freq, phase, wet, eb, (int)nE);

    // fused online-softmax attention, adds into ob (which holds skip)
    k_attn<<<(int)((n + 3) / 4), 256, 0, stream>>>(offs, src_s, eb, qb, kb, vb, ob, (int)n);

    // bn(relu(ob)) -> h (bf16)
    hipMemsetAsync(sums, 0, 2 * HID * sizeof(float), stream);
    k_bn_reduce<true><<<512, 256, 0, stream>>>(ob, (int)n, HID, 7, sums);
    k_bn_apply<true, false, true><<<4096, 256, 0, stream>>>(ob, (int)n, HID, sums,
                                                            bn_g + i * HID, bn_b + i * HID, h);
  }

  // MLP head on first B rows of h
  k_wt128<<<64, 256, 0, stream>>>(W1, w1t);
  k_mfma128<<<(B + 63) / 64, 256, 0, stream>>>(h, w1t, b1, z1, B);
  hipMemsetAsync(sums, 0, 2 * HID * sizeof(float), stream);
  k_bn_reduce<false><<<512, 256, 0, stream>>>(z1, B, HID, 7, sums);
  k_bn_apply<false, true, false><<<2048, 256, 0, stream>>>(z1, B, HID, sums, g1, be1, z1);
  k_gemm_64<<<(B + 15) / 16, 256, 0, stream>>>(z1, W2, b2, z2, B);
  hipMemsetAsync(sums, 0, 2 * 64 * sizeof(float), stream);
  k_bn_reduce<false><<<512, 256, 0, stream>>>(z2, B, 64, 6, sums);
  k_bn_apply<false, true, false><<<2048, 256, 0, stream>>>(z2, B, 64, sums, g2, be2, z2);
  k_final<<<(B + 3) / 4, 256, 0, stream>>>(z2, W3, b3, (float*)d_out, B);
}

// Round 4
// 1363.481 us; speedup vs baseline: 2.9897x; 1.0769x over previous
//
#include <hip/hip_runtime.h>
#include <hip/hip_bf16.h>
#include <math.h>

#define IN_DIM 172
#define HID 128
#define TDIM 100
#define KPAD 192

typedef __attribute__((ext_vector_type(8))) short bf16x8;
typedef __attribute__((ext_vector_type(4))) float f32x4;

static __device__ __forceinline__ ushort f2b(float x) {
  unsigned u = __float_as_uint(x);
  u += 0x7FFFu + ((u >> 16) & 1u);
  return (ushort)(u >> 16);
}
static __device__ __forceinline__ float blo(unsigned w) { return __uint_as_float(w << 16); }
static __device__ __forceinline__ float bhi(unsigned w) { return __uint_as_float(w & 0xffff0000u); }

// WpT[c][k] = bf16(Wp[k][c]), zero-padded k in [172,192)
__global__ void k_wpt(const float* __restrict__ Wp, ushort* __restrict__ wpt) {
  int i = blockIdx.x * 256 + threadIdx.x;
  if (i >= 128 * KPAD) return;
  int c = i / KPAD, k = i - c * KPAD;
  wpt[i] = (k < IN_DIM) ? f2b(Wp[k * HID + c]) : (ushort)0;
}

// h = relu(x_all[ids] @ Wp + bp) -> bf16, via MFMA, 64 rows/block
__global__ __launch_bounds__(256) void k_in_mfma(
    const float* __restrict__ x_all, const int* __restrict__ ids,
    const ushort* __restrict__ wpt, const float* __restrict__ bp,
    ushort* __restrict__ h, int n) {
  __shared__ __align__(16) ushort xs[64][200];
  int tid = threadIdx.x;
  long r0 = (long)blockIdx.x * 64;
  // zero the K-pad region [172,192) (and slack to 200)
  for (int i = tid; i < 64 * 28; i += 256) {
    int r = i / 28, c = IN_DIM + (i - r * 28);
    xs[r][c] = 0;
  }
  // gather + convert 64 rows x 172 cols (43 float4 per row)
  for (int i = tid; i < 64 * 43; i += 256) {
    int r = i / 43, seg = i - r * 43;
    long row = r0 + r;
    float4 v = make_float4(0.f, 0.f, 0.f, 0.f);
    if (row < n) v = *(const float4*)(x_all + (size_t)ids[row] * IN_DIM + seg * 4);
    ushort4 u;
    u.x = f2b(v.x); u.y = f2b(v.y); u.z = f2b(v.z); u.w = f2b(v.w);
    *(ushort4*)&xs[r][seg * 4] = u;
  }
  __syncthreads();
  int wv = tid >> 6, l = tid & 63;
  int arow = wv * 16 + (l & 15);
  int kb0 = (l >> 4) * 8;
  bf16x8 a[6];
  #pragma unroll
  for (int kk = 0; kk < 6; ++kk) a[kk] = *(const bf16x8*)&xs[arow][kk * 32 + kb0];
  #pragma unroll
  for (int nt = 0; nt < 8; ++nt) {
    int col = nt * 16 + (l & 15);
    const ushort* wcol = wpt + (size_t)col * KPAD + kb0;
    f32x4 acc = {0.f, 0.f, 0.f, 0.f};
    #pragma unroll
    for (int kk = 0; kk < 6; ++kk) {
      bf16x8 bfr = *(const bf16x8*)(wcol + kk * 32);
      acc = __builtin_amdgcn_mfma_f32_16x16x32_bf16(a[kk], bfr, acc, 0, 0, 0);
    }
    float bias = bp[col];
    #pragma unroll
    for (int j = 0; j < 4; ++j) {
      long row = r0 + wv * 16 + (l >> 4) * 4 + j;
      if (row < n) {
        float y = acc[j] + bias;
        h[row * HID + col] = f2b(y > 0.f ? y : 0.f);
      }
    }
  }
}

// pack WqT|WkT|WvT|WskipT -> wallT[512][128] bf16, biases -> ball[512]
__global__ void k_wprep(const float* __restrict__ Wq, const float* __restrict__ Wk,
                        const float* __restrict__ Wv, const float* __restrict__ Ws,
                        const float* __restrict__ bq, const float* __restrict__ bk,
                        const float* __restrict__ bv, const float* __restrict__ bs,
                        ushort* __restrict__ wallT, float* __restrict__ ball) {
  int i = blockIdx.x * 256 + threadIdx.x;
  if (i >= 512 * 128) return;
  int col = i >> 7, k = i & 127;
  int m = col >> 7, c = col & 127;
  const float* W = (m == 0) ? Wq : (m == 1) ? Wk : (m == 2) ? Wv : Ws;
  wallT[i] = f2b(W[k * HID + c]);
  if (k == 0) {
    const float* bb = (m == 0) ? bq : (m == 1) ? bk : (m == 2) ? bv : bs;
    ball[col] = bb[c];
  }
}

// W1T[c][k] = bf16(W1[k][c])
__global__ void k_wt128(const float* __restrict__ W, ushort* __restrict__ wt) {
  int i = blockIdx.x * 256 + threadIdx.x;
  if (i >= 128 * 128) return;
  int c = i >> 7, k = i & 127;
  wt[i] = f2b(W[k * HID + c]);
}

// fused q/k/v/skip: y = h @ [Wq|Wk|Wv|Ws] + b; q,k,v bf16; skip f32 -> ob
__global__ __launch_bounds__(256) void k_qkvs(
    const ushort* __restrict__ h, const ushort* __restrict__ wallT,
    const float* __restrict__ ball,
    ushort* __restrict__ qb, ushort* __restrict__ kbuf, ushort* __restrict__ vb,
    float* __restrict__ ob, int n) {
  __shared__ __align__(16) ushort hs[64][136];
  int tid = threadIdx.x;
  long r0 = (long)blockIdx.x * 64;
  bf16x8 zv = {0, 0, 0, 0, 0, 0, 0, 0};
  for (int i = tid; i < 64 * 16; i += 256) {
    int r = i >> 4, cseg = i & 15;
    long row = r0 + r;
    bf16x8 v = (row < n) ? *(const bf16x8*)&h[row * HID + cseg * 8] : zv;
    *(bf16x8*)&hs[r][cseg * 8] = v;
  }
  __syncthreads();
  int wv = tid >> 6, l = tid & 63;
  int arow = wv * 16 + (l & 15);
  int kb0 = (l >> 4) * 8;
  bf16x8 a[4];
  #pragma unroll
  for (int kk = 0; kk < 4; ++kk) a[kk] = *(const bf16x8*)&hs[arow][kk * 32 + kb0];
  #pragma unroll 4
  for (int nt = 0; nt < 32; ++nt) {
    int col = nt * 16 + (l & 15);
    const ushort* wcol = wallT + (size_t)col * 128 + kb0;
    f32x4 acc = {0.f, 0.f, 0.f, 0.f};
    #pragma unroll
    for (int kk = 0; kk < 4; ++kk) {
      bf16x8 bfr = *(const bf16x8*)(wcol + kk * 32);
      acc = __builtin_amdgcn_mfma_f32_16x16x32_bf16(a[kk], bfr, acc, 0, 0, 0);
    }
    float bias = ball[col];
    int m = col >> 7, c = col & 127;
    #pragma unroll
    for (int j = 0; j < 4; ++j) {
      long row = r0 + wv * 16 + (l >> 4) * 4 + j;
      if (row < n) {
        float y = acc[j] + bias;
        if (m == 3) ob[row * HID + c] = y;
        else {
          ushort* db = (m == 0) ? qb : (m == 1) ? kbuf : vb;
          db[row * HID + c] = f2b(y);
        }
      }
    }
  }
}

// y = X(bf16) @ WT + b -> f32, 64 rows/block
__global__ __launch_bounds__(256) void k_mfma128(
    const ushort* __restrict__ X, const ushort* __restrict__ WT,
    const float* __restrict__ bias, float* __restrict__ Y, int n) {
  __shared__ __align__(16) ushort hs[64][136];
  int tid = threadIdx.x;
  long r0 = (long)blockIdx.x * 64;
  bf16x8 zv = {0, 0, 0, 0, 0, 0, 0, 0};
  for (int i = tid; i < 64 * 16; i += 256) {
    int r = i >> 4, cseg = i & 15;
    long row = r0 + r;
    bf16x8 v = (row < n) ? *(const bf16x8*)&X[row * HID + cseg * 8] : zv;
    *(bf16x8*)&hs[r][cseg * 8] = v;
  }
  __syncthreads();
  int wv = tid >> 6, l = tid & 63;
  int arow = wv * 16 + (l & 15);
  int kb0 = (l >> 4) * 8;
  bf16x8 a[4];
  #pragma unroll
  for (int kk = 0; kk < 4; ++kk) a[kk] = *(const bf16x8*)&hs[arow][kk * 32 + kb0];
  #pragma unroll
  for (int nt = 0; nt < 8; ++nt) {
    int col = nt * 16 + (l & 15);
    const ushort* wcol = WT + (size_t)col * 128 + kb0;
    f32x4 acc = {0.f, 0.f, 0.f, 0.f};
    #pragma unroll
    for (int kk = 0; kk < 4; ++kk) {
      bf16x8 bfr = *(const bf16x8*)(wcol + kk * 32);
      acc = __builtin_amdgcn_mfma_f32_16x16x32_bf16(a[kk], bfr, acc, 0, 0, 0);
    }
    float bs = bias[col];
    #pragma unroll
    for (int j = 0; j < 4; ++j) {
      long row = r0 + wv * 16 + (l >> 4) * 4 + j;
      if (row < n) Y[row * HID + col] = acc[j] + bs;
    }
  }
}

// ---- counting sort by dst ----
__global__ void k_hist(const int* __restrict__ dst, int* __restrict__ counts, int nE) {
  int e = blockIdx.x * 256 + threadIdx.x;
  if (e < nE) atomicAdd(&counts[dst[e]], 1);
}

__global__ void k_scan_chunk(const int* __restrict__ counts, int* __restrict__ offs,
                             int* __restrict__ chunkSums, int n) {
  __shared__ int ls[256];
  int t = threadIdx.x;
  int base = blockIdx.x * 1024 + t * 4;
  int v[4];
  #pragma unroll
  for (int j = 0; j < 4; ++j) v[j] = (base + j < n) ? counts[base + j] : 0;
  ls[t] = v[0] + v[1] + v[2] + v[3];
  __syncthreads();
  for (int off = 1; off < 256; off <<= 1) {
    int x = (t >= off) ? ls[t - off] : 0;
    __syncthreads();
    ls[t] += x;
    __syncthreads();
  }
  int run = (t == 0) ? 0 : ls[t - 1];
  if (t == 255) chunkSums[blockIdx.x] = ls[255];
  #pragma unroll
  for (int j = 0; j < 4; ++j) {
    if (base + j < n) offs[base + j] = run;
    run += v[j];
  }
}

__global__ void k_scan_tops(int* __restrict__ chunkSums, int nchunks) {
  __shared__ int ls[256];
  int t = threadIdx.x;
  ls[t] = (t < nchunks) ? chunkSums[t] : 0;
  __syncthreads();
  for (int off = 1; off < 256; off <<= 1) {
    int x = (t >= off) ? ls[t - off] : 0;
    __syncthreads();
    ls[t] += x;
    __syncthreads();
  }
  int excl = (t == 0) ? 0 : ls[t - 1];
  if (t < nchunks) chunkSums[t] = excl;
}

__global__ void k_scan_add(int* __restrict__ offs, const int* __restrict__ chunkSums,
                           int n, int nE) {
  int i = blockIdx.x * 256 + threadIdx.x;
  if (i < n) offs[i] += chunkSums[i >> 10];
  if (i == 0) offs[n] = nE;
}

__global__ void k_scatter(const int* __restrict__ src, const int* __restrict__ dst,
                          const float* __restrict__ dts, const int* __restrict__ offs,
                          int* __restrict__ cursor, int* __restrict__ src_s,
                          float* __restrict__ dts_s, int nE) {
  int e = blockIdx.x * 256 + threadIdx.x;
  if (e >= nE) return;
  int d = dst[e];
  int pos = offs[d] + atomicAdd(&cursor[d], 1);
  src_s[pos] = src[e];
  dts_s[pos] = dts[e];
}

// WeT[c][t] = bf16(We[t][c]), zero-padded t in [100,128)
__global__ void k_wet(const float* __restrict__ We, ushort* __restrict__ wet) {
  int i = blockIdx.x * 256 + threadIdx.x;
  if (i >= 128 * 128) return;
  int c = i >> 7, t = i & 127;
  wet[i] = (t < TDIM) ? f2b(We[t * HID + c]) : (ushort)0;
}

// e[E][128] = cos(dt*f+p) @ We via MFMA, bf16 out (sorted dts)
__global__ __launch_bounds__(256) void k_te_mfma(
    const float* __restrict__ dts, const float* __restrict__ freq,
    const float* __restrict__ phase, const ushort* __restrict__ wet,
    ushort* __restrict__ eb, int nE) {
  __shared__ __align__(16) ushort te[64][136];
  __shared__ float dt_s[64];
  __shared__ float fr_s[128], ph_s[128];
  int tid = threadIdx.x;
  if (tid < 128) {
    fr_s[tid] = (tid < TDIM) ? freq[tid] : 0.f;
    ph_s[tid] = (tid < TDIM) ? phase[tid] : 0.f;
  }
  long e0 = (long)blockIdx.x << 6;
  if (tid < 64) dt_s[tid] = (e0 + tid < nE) ? dts[e0 + tid] : 0.f;
  __syncthreads();
  for (int i = tid; i < 64 * 128; i += 256) {
    int el = i >> 7, t = i & 127;
    float val = (t < TDIM) ? __cosf(dt_s[el] * fr_s[t] + ph_s[t]) : 0.f;
    te[el][t] = f2b(val);
  }
  __syncthreads();
  int wv = tid >> 6, l = tid & 63;
  int arow = wv * 16 + (l & 15);
  int kb0 = (l >> 4) * 8;
  bf16x8 a[4];
  #pragma unroll
  for (int kk = 0; kk < 4; ++kk) a[kk] = *(const bf16x8*)&te[arow][kk * 32 + kb0];
  #pragma unroll
  for (int nt = 0; nt < 8; ++nt) {
    int col = nt * 16 + (l & 15);
    const ushort* wcol = wet + (size_t)col * 128 + kb0;
    f32x4 acc = {0.f, 0.f, 0.f, 0.f};
    #pragma unroll
    for (int kk = 0; kk < 4; ++kk) {
      bf16x8 bfr = *(const bf16x8*)(wcol + kk * 32);
      acc = __builtin_amdgcn_mfma_f32_16x16x32_bf16(a[kk], bfr, acc, 0, 0, 0);
    }
    #pragma unroll
    for (int j = 0; j < 4; ++j) {
      long row = e0 + wv * 16 + (l >> 4) * 4 + j;
      if (row < nE) eb[row * 128 + col] = f2b(acc[j]);
    }
  }
}

// fused attention: one wave per dst, online softmax + weighted V accumulation
__global__ void k_attn(const int* __restrict__ offs, const int* __restrict__ src_s,
                       const ushort* __restrict__ eb, const ushort* __restrict__ qb,
                       const ushort* __restrict__ kb, const ushort* __restrict__ vb,
                       float* __restrict__ ob, int n) {
  int d = (blockIdx.x * 256 + threadIdx.x) >> 6;
  if (d >= n) return;
  int lane = threadIdx.x & 63;
  int c0 = lane * 2;
  int beg = offs[d], end = offs[d + 1];
  if (beg == end) return;
  unsigned qw = *(const unsigned*)(qb + (size_t)d * HID + c0);
  float q0 = blo(qw), q1 = bhi(qw);
  float m = -INFINITY, s = 0.f, acc0 = 0.f, acc1 = 0.f;
  for (int pos = beg; pos < end; ++pos) {
    int sv = src_s[pos];
    unsigned kw = *(const unsigned*)(kb + (size_t)sv * HID + c0);
    unsigned vw = *(const unsigned*)(vb + (size_t)sv * HID + c0);
    unsigned ew = *(const unsigned*)(eb + (size_t)pos * HID + c0);
    float e0 = blo(ew), e1 = bhi(ew);
    float p = q0 * (blo(kw) + e0) + q1 * (bhi(kw) + e1);
    p += __shfl_xor(p, 1);
    p += __shfl_xor(p, 2);
    p += __shfl_xor(p, 4);
    p += __shfl_xor(p, 8);
    float a = p * 0.17677669529663687f;  // 1/sqrt(32)
    float nm = fmaxf(m, a);
    float sc = __expf(m - nm);
    float pe = __expf(a - nm);
    s = s * sc + pe;
    acc0 = acc0 * sc + pe * (blo(vw) + e0);
    acc1 = acc1 * sc + pe * (bhi(vw) + e1);
    m = nm;
  }
  float inv = 1.f / (s + 1e-16f);
  float* orow = ob + (size_t)d * HID + c0;
  orow[0] += acc0 * inv;
  orow[1] += acc1 * inv;
}

template <bool PRE_RELU>
__global__ void k_bn_reduce(const float* __restrict__ X, int n, int C, int shift,
                            float* __restrict__ sums) {
  int col = threadIdx.x & (C - 1);
  int rloc = threadIdx.x >> shift;
  int rpt = 256 >> shift;
  float s = 0.f, s2 = 0.f;
  for (long r = (long)blockIdx.x * rpt + rloc; r < n; r += (long)gridDim.x * rpt) {
    float v = X[r * C + col];
    if (PRE_RELU) v = v > 0.f ? v : 0.f;
    s += v; s2 += v * v;
  }
  __shared__ float ls[256], ls2[256];
  ls[threadIdx.x] = s; ls2[threadIdx.x] = s2;
  __syncthreads();
  if (rloc == 0) {
    for (int j = 1; j < rpt; ++j) { s += ls[j * C + col]; s2 += ls2[j * C + col]; }
    atomicAdd(&sums[col], s);
    atomicAdd(&sums[C + col], s2);
  }
}

template <bool PRE_RELU, bool POST_RELU, bool BF16OUT>
__global__ void k_bn_apply(const float* __restrict__ X, int n, int C,
                           const float* __restrict__ sums,
                           const float* __restrict__ g, const float* __restrict__ b,
                           void* __restrict__ Yv) {
  long total = (long)n * C;
  float inv_n = 1.f / (float)n;
  for (long i = (long)blockIdx.x * 256 + threadIdx.x; i < total; i += (long)gridDim.x * 256) {
    int col = (int)(i & (C - 1));
    float mean = sums[col] * inv_n;
    float var = sums[C + col] * inv_n - mean * mean;
    float v = X[i];
    if (PRE_RELU) v = v > 0.f ? v : 0.f;
    v = g[col] * (v - mean) * rsqrtf(var + 1e-5f) + b[col];
    if (POST_RELU) v = v > 0.f ? v : 0.f;
    if (BF16OUT) ((ushort*)Yv)[i] = f2b(v);
    else ((float*)Yv)[i] = v;
  }
}

// Y = X @ W + b (X: n x 128 f32, W: 128 x 64), 16 rows/block
__global__ __launch_bounds__(256) void k_gemm_64(
    const float* __restrict__ X, const float* __restrict__ W,
    const float* __restrict__ b, float* __restrict__ Y, int n) {
  __shared__ float xs[16][HID];
  int r0 = blockIdx.x * 16;
  for (int idx = threadIdx.x; idx < 16 * HID; idx += 256) {
    int r = idx >> 7, c = idx & 127;
    int row = r0 + r;
    xs[r][c] = (row < n) ? X[(size_t)row * HID + c] : 0.f;
  }
  __syncthreads();
  int col = threadIdx.x & 63;
  int rg = threadIdx.x >> 6;
  float acc[4] = {0.f, 0.f, 0.f, 0.f};
  #pragma unroll 4
  for (int kk = 0; kk < HID; ++kk) {
    float w = W[kk * 64 + col];
    #pragma unroll
    for (int j = 0; j < 4; ++j) acc[j] += xs[rg + 4 * j][kk] * w;
  }
  float bias = b[col];
  #pragma unroll
  for (int j = 0; j < 4; ++j) {
    int row = r0 + rg + 4 * j;
    if (row < n) Y[(size_t)row * 64 + col] = acc[j] + bias;
  }
}

__global__ __launch_bounds__(256) void k_final(
    const float* __restrict__ z2, const float* __restrict__ W3,
    const float* __restrict__ b3, float* __restrict__ out, int n) {
  int wave = threadIdx.x >> 6, lane = threadIdx.x & 63;
  int row = blockIdx.x * 4 + wave;
  if (row >= n) return;
  float pv = z2[(size_t)row * 64 + lane] * W3[lane];
  pv += __shfl_xor(pv, 1);
  pv += __shfl_xor(pv, 2);
  pv += __shfl_xor(pv, 4);
  pv += __shfl_xor(pv, 8);
  pv += __shfl_xor(pv, 16);
  pv += __shfl_xor(pv, 32);
  if (lane == 0) out[row] = pv + b3[0];
}

extern "C" void kernel_launch(void* const* d_in, const int* in_sizes, int n_in,
                              void* d_out, int out_size, void* d_ws, size_t ws_size,
                              hipStream_t stream) {
  const float* x_all = (const float*)d_in[0];
  const int* ids = (const int*)d_in[1];
  const int* esrc = (const int*)d_in[2];
  const int* edst = (const int*)d_in[3];
  const float* dts = (const float*)d_in[4];
  const float* freq = (const float*)d_in[6];
  const float* phase = (const float*)d_in[7];
  const float* Wp = (const float*)d_in[8];
  const float* bp = (const float*)d_in[9];
  const float* Wq = (const float*)d_in[10];
  const float* bq = (const float*)d_in[11];
  const float* Wk = (const float*)d_in[12];
  const float* bk = (const float*)d_in[13];
  const float* Wv = (const float*)d_in[14];
  const float* bv = (const float*)d_in[15];
  const float* We = (const float*)d_in[16];
  const float* Wskip = (const float*)d_in[17];
  const float* bskip = (const float*)d_in[18];
  const float* bn_g = (const float*)d_in[19];
  const float* bn_b = (const float*)d_in[20];
  const float* W1 = (const float*)d_in[21];
  const float* b1 = (const float*)d_in[22];
  const float* g1 = (const float*)d_in[23];
  const float* be1 = (const float*)d_in[24];
  const float* W2 = (const float*)d_in[25];
  const float* b2 = (const float*)d_in[26];
  const float* g2 = (const float*)d_in[27];
  const float* be2 = (const float*)d_in[28];
  const float* W3 = (const float*)d_in[29];
  const float* b3 = (const float*)d_in[30];

  size_t n = (size_t)in_sizes[1];
  size_t nE = (size_t)in_sizes[2] / 2;
  int B = out_size;

  char* pc = (char*)d_ws;
  auto alloc = [&](size_t bytes) { char* r = pc; pc += (bytes + 255) & ~(size_t)255; return r; };
  ushort* h    = (ushort*)alloc(n * HID * 2);
  ushort* qb   = (ushort*)alloc(n * HID * 2);
  ushort* kb   = (ushort*)alloc(n * HID * 2);
  ushort* vb   = (ushort*)alloc(n * HID * 2);
  float*  ob   = (float*)alloc(n * HID * 4);
  ushort* eb   = (ushort*)alloc(nE * HID * 2);
  int* src_s   = (int*)alloc(nE * 4);
  float* dts_s = (float*)alloc(nE * 4);
  int* counts  = (int*)alloc(n * 4);
  int* cursor  = (int*)alloc(n * 4);
  int* offs    = (int*)alloc((n + 1) * 4);
  int* chunkS  = (int*)alloc(256 * 4);
  ushort* wallT = (ushort*)alloc(512 * 128 * 2);
  float* ball  = (float*)alloc(512 * 4);
  ushort* wet  = (ushort*)alloc(128 * 128 * 2);
  ushort* w1t  = (ushort*)alloc(128 * 128 * 2);
  ushort* wpt  = (ushort*)alloc(128 * KPAD * 2);
  float* sums  = (float*)alloc(256 * 4);
  float* z1    = (float*)alloc((size_t)B * HID * 4);
  float* z2    = (float*)alloc((size_t)B * 64 * 4);

  int gn64 = (int)((n + 63) / 64);
  int ge256 = (int)((nE + 255) / 256);
  int eblk = (int)((nE + 63) / 64);
  int nchunks = (int)((n + 1023) / 1024);

  k_wpt<<<(128 * KPAD + 255) / 256, 256, 0, stream>>>(Wp, wpt);
  k_in_mfma<<<gn64, 256, 0, stream>>>(x_all, ids, wpt, bp, h, (int)n);

  for (int i = 0; i < 2; ++i) {
    const int* src_i = esrc + i * nE;
    const int* dst_i = edst + i * nE;
    const float* dts_i = dts + i * nE;
    const float* We_i = We + (size_t)i * TDIM * HID;

    k_wprep<<<256, 256, 0, stream>>>(Wq + (size_t)i * HID * HID, Wk + (size_t)i * HID * HID,
                                     Wv + (size_t)i * HID * HID, Wskip + (size_t)i * HID * HID,
                                     bq + i * HID, bk + i * HID, bv + i * HID, bskip + i * HID,
                                     wallT, ball);
    k_qkvs<<<gn64, 256, 0, stream>>>(h, wallT, ball, qb, kb, vb, ob, (int)n);

    // counting sort by dst
    hipMemsetAsync(counts, 0, n * 4, stream);
    hipMemsetAsync(cursor, 0, n * 4, stream);
    k_hist<<<ge256, 256, 0, stream>>>(dst_i, counts, (int)nE);
    k_scan_chunk<<<nchunks, 256, 0, stream>>>(counts, offs, chunkS, (int)n);
    k_scan_tops<<<1, 256, 0, stream>>>(chunkS, nchunks);
    k_scan_add<<<(int)((n + 255) / 256), 256, 0, stream>>>(offs, chunkS, (int)n, (int)nE);
    k_scatter<<<ge256, 256, 0, stream>>>(src_i, dst_i, dts_i, offs, cursor, src_s, dts_s, (int)nE);

    // e = cos(dt f + p) @ We, in sorted order
    k_wet<<<64, 256, 0, stream>>>(We_i, wet);
    k_te_mfma<<<eblk, 256, 0, stream>>>(dts_s, freq, phase, wet, eb, (int)nE);

    // fused online-softmax attention, adds into ob (which holds skip)
    k_attn<<<(int)((n + 3) / 4), 256, 0, stream>>>(offs, src_s, eb, qb, kb, vb, ob, (int)n);

    // bn(relu(ob)) -> h (bf16)
    hipMemsetAsync(sums, 0, 2 * HID * sizeof(float), stream);
    k_bn_reduce<true><<<512, 256, 0, stream>>>(ob, (int)n, HID, 7, sums);
    k_bn_apply<true, false, true><<<4096, 256, 0, stream>>>(ob, (int)n, HID, sums,
                                                            bn_g + i * HID, bn_b + i * HID, h);
  }

  // MLP head on first B rows of h
  k_wt128<<<64, 256, 0, stream>>>(W1, w1t);
  k_mfma128<<<(B + 63) / 64, 256, 0, stream>>>(h, w1t, b1, z1, B);
  hipMemsetAsync(sums, 0, 2 * HID * sizeof(float), stream);
  k_bn_reduce<false><<<512, 256, 0, stream>>>(z1, B, HID, 7, sums);
  k_bn_apply<false, true, false><<<2048, 256, 0, stream>>>(z1, B, HID, sums, g1, be1, z1);
  k_gemm_64<<<(B + 15) / 16, 256, 0, stream>>>(z1, W2, b2, z2, B);
  hipMemsetAsync(sums, 0, 2 * 64 * sizeof(float), stream);
  k_bn_reduce<false><<<512, 256, 0, stream>>>(z2, B, 64, 6, sums);
  k_bn_apply<false, true, false><<<2048, 256, 0, stream>>>(z2, B, 64, sums, g2, be2, z2);
  k_final<<<(B + 3) / 4, 256, 0, stream>>>(z2, W3, b3, (float*)d_out, B);
}

// Round 5
// 1109.697 us; speedup vs baseline: 3.6734x; 1.2287x over previous
//
#include <hip/hip_runtime.h>
#include <hip/hip_bf16.h>
#include <math.h>

#define IN_DIM 172
#define HID 128
#define TDIM 100
#define KPAD 192

typedef __attribute__((ext_vector_type(8))) short bf16x8;
typedef __attribute__((ext_vector_type(4))) float f32x4;

static __device__ __forceinline__ ushort f2b(float x) {
  unsigned u = __float_as_uint(x);
  u += 0x7FFFu + ((u >> 16) & 1u);
  return (ushort)(u >> 16);
}
static __device__ __forceinline__ float blo(unsigned w) { return __uint_as_float(w << 16); }
static __device__ __forceinline__ float bhi(unsigned w) { return __uint_as_float(w & 0xffff0000u); }

// WpT[c][k] = bf16(Wp[k][c]), zero-padded k in [172,192)
__global__ void k_wpt(const float* __restrict__ Wp, ushort* __restrict__ wpt) {
  int i = blockIdx.x * 256 + threadIdx.x;
  if (i >= 128 * KPAD) return;
  int c = i / KPAD, k = i - c * KPAD;
  wpt[i] = (k < IN_DIM) ? f2b(Wp[k * HID + c]) : (ushort)0;
}

// h = relu(x_all[ids] @ Wp + bp) -> bf16, via MFMA, 64 rows/block
__global__ __launch_bounds__(256) void k_in_mfma(
    const float* __restrict__ x_all, const int* __restrict__ ids,
    const ushort* __restrict__ wpt, const float* __restrict__ bp,
    ushort* __restrict__ h, int n) {
  __shared__ __align__(16) ushort xs[64][200];
  int tid = threadIdx.x;
  long r0 = (long)blockIdx.x * 64;
  for (int i = tid; i < 64 * 28; i += 256) {
    int r = i / 28, c = IN_DIM + (i - r * 28);
    xs[r][c] = 0;
  }
  for (int i = tid; i < 64 * 43; i += 256) {
    int r = i / 43, seg = i - r * 43;
    long row = r0 + r;
    float4 v = make_float4(0.f, 0.f, 0.f, 0.f);
    if (row < n) v = *(const float4*)(x_all + (size_t)ids[row] * IN_DIM + seg * 4);
    ushort4 u;
    u.x = f2b(v.x); u.y = f2b(v.y); u.z = f2b(v.z); u.w = f2b(v.w);
    *(ushort4*)&xs[r][seg * 4] = u;
  }
  __syncthreads();
  int wv = tid >> 6, l = tid & 63;
  int arow = wv * 16 + (l & 15);
  int kb0 = (l >> 4) * 8;
  bf16x8 a[6];
  #pragma unroll
  for (int kk = 0; kk < 6; ++kk) a[kk] = *(const bf16x8*)&xs[arow][kk * 32 + kb0];
  #pragma unroll
  for (int nt = 0; nt < 8; ++nt) {
    int col = nt * 16 + (l & 15);
    const ushort* wcol = wpt + (size_t)col * KPAD + kb0;
    f32x4 acc = {0.f, 0.f, 0.f, 0.f};
    #pragma unroll
    for (int kk = 0; kk < 6; ++kk) {
      bf16x8 bfr = *(const bf16x8*)(wcol + kk * 32);
      acc = __builtin_amdgcn_mfma_f32_16x16x32_bf16(a[kk], bfr, acc, 0, 0, 0);
    }
    float bias = bp[col];
    #pragma unroll
    for (int j = 0; j < 4; ++j) {
      long row = r0 + wv * 16 + (l >> 4) * 4 + j;
      if (row < n) {
        float y = acc[j] + bias;
        h[row * HID + col] = f2b(y > 0.f ? y : 0.f);
      }
    }
  }
}

// pack WqT|WkT|WvT|WskipT -> wallT[512][128] bf16, biases -> ball[512]
__global__ void k_wprep(const float* __restrict__ Wq, const float* __restrict__ Wk,
                        const float* __restrict__ Wv, const float* __restrict__ Ws,
                        const float* __restrict__ bq, const float* __restrict__ bk,
                        const float* __restrict__ bv, const float* __restrict__ bs,
                        ushort* __restrict__ wallT, float* __restrict__ ball) {
  int i = blockIdx.x * 256 + threadIdx.x;
  if (i >= 512 * 128) return;
  int col = i >> 7, k = i & 127;
  int m = col >> 7, c = col & 127;
  const float* W = (m == 0) ? Wq : (m == 1) ? Wk : (m == 2) ? Wv : Ws;
  wallT[i] = f2b(W[k * HID + c]);
  if (k == 0) {
    const float* bb = (m == 0) ? bq : (m == 1) ? bk : (m == 2) ? bv : bs;
    ball[col] = bb[c];
  }
}

// W1T[c][k] = bf16(W1[k][c])
__global__ void k_wt128(const float* __restrict__ W, ushort* __restrict__ wt) {
  int i = blockIdx.x * 256 + threadIdx.x;
  if (i >= 128 * 128) return;
  int c = i >> 7, k = i & 127;
  wt[i] = f2b(W[k * HID + c]);
}

// fused q/k/v/skip: 128 rows/block, 512 thr, weights staged via LDS in 64-col groups
__global__ __launch_bounds__(512) void k_qkvs(
    const ushort* __restrict__ h, const ushort* __restrict__ wallT,
    const float* __restrict__ ball,
    ushort* __restrict__ qb, ushort* __restrict__ kbuf, ushort* __restrict__ vb,
    float* __restrict__ ob, int n) {
  __shared__ __align__(16) ushort hs[128][136];
  __shared__ __align__(16) ushort ws[64][136];
  int tid = threadIdx.x;
  long r0 = (long)blockIdx.x * 128;
  bf16x8 zv = {0, 0, 0, 0, 0, 0, 0, 0};
  for (int i = tid; i < 128 * 16; i += 512) {
    int r = i >> 4, cseg = i & 15;
    long row = r0 + r;
    bf16x8 v = (row < n) ? *(const bf16x8*)&h[row * HID + cseg * 8] : zv;
    *(bf16x8*)&hs[r][cseg * 8] = v;
  }
  __syncthreads();
  int wv = tid >> 6, l = tid & 63;
  int arow = wv * 16 + (l & 15);
  int kb0 = (l >> 4) * 8;
  bf16x8 a[4];
  #pragma unroll
  for (int kk = 0; kk < 4; ++kk) a[kk] = *(const bf16x8*)&hs[arow][kk * 32 + kb0];

  for (int g = 0; g < 8; ++g) {
    __syncthreads();
    for (int i = tid; i < 64 * 16; i += 512) {
      int c = i >> 4, cseg = i & 15;
      *(bf16x8*)&ws[c][cseg * 8] =
          *(const bf16x8*)&wallT[(size_t)(g * 64 + c) * 128 + cseg * 8];
    }
    __syncthreads();
    #pragma unroll
    for (int nt = 0; nt < 4; ++nt) {
      int colc = nt * 16 + (l & 15);
      int gcol = g * 64 + colc;
      f32x4 acc = {0.f, 0.f, 0.f, 0.f};
      #pragma unroll
      for (int kk = 0; kk < 4; ++kk) {
        bf16x8 bfr = *(const bf16x8*)&ws[colc][kk * 32 + kb0];
        acc = __builtin_amdgcn_mfma_f32_16x16x32_bf16(a[kk], bfr, acc, 0, 0, 0);
      }
      float bias = ball[gcol];
      int m = gcol >> 7, c = gcol & 127;
      #pragma unroll
      for (int j = 0; j < 4; ++j) {
        long row = r0 + wv * 16 + (l >> 4) * 4 + j;
        if (row < n) {
          float y = acc[j] + bias;
          if (m == 3) ob[row * HID + c] = y;
          else {
            ushort* db = (m == 0) ? qb : (m == 1) ? kbuf : vb;
            db[row * HID + c] = f2b(y);
          }
        }
      }
    }
  }
}

// y = X(bf16) @ WT + b -> f32, 64 rows/block
__global__ __launch_bounds__(256) void k_mfma128(
    const ushort* __restrict__ X, const ushort* __restrict__ WT,
    const float* __restrict__ bias, float* __restrict__ Y, int n) {
  __shared__ __align__(16) ushort hs[64][136];
  int tid = threadIdx.x;
  long r0 = (long)blockIdx.x * 64;
  bf16x8 zv = {0, 0, 0, 0, 0, 0, 0, 0};
  for (int i = tid; i < 64 * 16; i += 256) {
    int r = i >> 4, cseg = i & 15;
    long row = r0 + r;
    bf16x8 v = (row < n) ? *(const bf16x8*)&X[row * HID + cseg * 8] : zv;
    *(bf16x8*)&hs[r][cseg * 8] = v;
  }
  __syncthreads();
  int wv = tid >> 6, l = tid & 63;
  int arow = wv * 16 + (l & 15);
  int kb0 = (l >> 4) * 8;
  bf16x8 a[4];
  #pragma unroll
  for (int kk = 0; kk < 4; ++kk) a[kk] = *(const bf16x8*)&hs[arow][kk * 32 + kb0];
  #pragma unroll
  for (int nt = 0; nt < 8; ++nt) {
    int col = nt * 16 + (l & 15);
    const ushort* wcol = WT + (size_t)col * 128 + kb0;
    f32x4 acc = {0.f, 0.f, 0.f, 0.f};
    #pragma unroll
    for (int kk = 0; kk < 4; ++kk) {
      bf16x8 bfr = *(const bf16x8*)(wcol + kk * 32);
      acc = __builtin_amdgcn_mfma_f32_16x16x32_bf16(a[kk], bfr, acc, 0, 0, 0);
    }
    float bs = bias[col];
    #pragma unroll
    for (int j = 0; j < 4; ++j) {
      long row = r0 + wv * 16 + (l >> 4) * 4 + j;
      if (row < n) Y[row * HID + col] = acc[j] + bs;
    }
  }
}

// ---- counting sort by dst ----
__global__ void k_hist(const int* __restrict__ dst, int* __restrict__ counts, int nE) {
  int e = blockIdx.x * 256 + threadIdx.x;
  if (e < nE) atomicAdd(&counts[dst[e]], 1);
}

__global__ void k_scan_chunk(const int* __restrict__ counts, int* __restrict__ offs,
                             int* __restrict__ chunkSums, int n) {
  __shared__ int ls[256];
  int t = threadIdx.x;
  int base = blockIdx.x * 1024 + t * 4;
  int v[4];
  #pragma unroll
  for (int j = 0; j < 4; ++j) v[j] = (base + j < n) ? counts[base + j] : 0;
  ls[t] = v[0] + v[1] + v[2] + v[3];
  __syncthreads();
  for (int off = 1; off < 256; off <<= 1) {
    int x = (t >= off) ? ls[t - off] : 0;
    __syncthreads();
    ls[t] += x;
    __syncthreads();
  }
  int run = (t == 0) ? 0 : ls[t - 1];
  if (t == 255) chunkSums[blockIdx.x] = ls[255];
  #pragma unroll
  for (int j = 0; j < 4; ++j) {
    if (base + j < n) offs[base + j] = run;
    run += v[j];
  }
}

__global__ void k_scan_tops(int* __restrict__ chunkSums, int nchunks) {
  __shared__ int ls[256];
  int t = threadIdx.x;
  ls[t] = (t < nchunks) ? chunkSums[t] : 0;
  __syncthreads();
  for (int off = 1; off < 256; off <<= 1) {
    int x = (t >= off) ? ls[t - off] : 0;
    __syncthreads();
    ls[t] += x;
    __syncthreads();
  }
  int excl = (t == 0) ? 0 : ls[t - 1];
  if (t < nchunks) chunkSums[t] = excl;
}

__global__ void k_scan_add(int* __restrict__ offs, const int* __restrict__ chunkSums,
                           int n, int nE) {
  int i = blockIdx.x * 256 + threadIdx.x;
  if (i < n) offs[i] += chunkSums[i >> 10];
  if (i == 0) offs[n] = nE;
}

__global__ void k_scatter(const int* __restrict__ src, const int* __restrict__ dst,
                          const float* __restrict__ dts, const int* __restrict__ offs,
                          int* __restrict__ cursor, int* __restrict__ src_s,
                          float* __restrict__ dts_s, int nE) {
  int e = blockIdx.x * 256 + threadIdx.x;
  if (e >= nE) return;
  int d = dst[e];
  int pos = offs[d] + atomicAdd(&cursor[d], 1);
  src_s[pos] = src[e];
  dts_s[pos] = dts[e];
}

// WeT[c][t] = bf16(We[t][c]), zero-padded t in [100,128)
__global__ void k_wet(const float* __restrict__ We, ushort* __restrict__ wet) {
  int i = blockIdx.x * 256 + threadIdx.x;
  if (i >= 128 * 128) return;
  int c = i >> 7, t = i & 127;
  wet[i] = (t < TDIM) ? f2b(We[t * HID + c]) : (ushort)0;
}

// e[E][128] = cos(dt*f+p) @ We via MFMA, bf16 out (sorted dts)
__global__ __launch_bounds__(256) void k_te_mfma(
    const float* __restrict__ dts, const float* __restrict__ freq,
    const float* __restrict__ phase, const ushort* __restrict__ wet,
    ushort* __restrict__ eb, int nE) {
  __shared__ __align__(16) ushort te[64][136];
  __shared__ float dt_s[64];
  __shared__ float fr_s[128], ph_s[128];
  int tid = threadIdx.x;
  if (tid < 128) {
    fr_s[tid] = (tid < TDIM) ? freq[tid] : 0.f;
    ph_s[tid] = (tid < TDIM) ? phase[tid] : 0.f;
  }
  long e0 = (long)blockIdx.x << 6;
  if (tid < 64) dt_s[tid] = (e0 + tid < nE) ? dts[e0 + tid] : 0.f;
  __syncthreads();
  for (int i = tid; i < 64 * 128; i += 256) {
    int el = i >> 7, t = i & 127;
    float val = (t < TDIM) ? __cosf(dt_s[el] * fr_s[t] + ph_s[t]) : 0.f;
    te[el][t] = f2b(val);
  }
  __syncthreads();
  int wv = tid >> 6, l = tid & 63;
  int arow = wv * 16 + (l & 15);
  int kb0 = (l >> 4) * 8;
  bf16x8 a[4];
  #pragma unroll
  for (int kk = 0; kk < 4; ++kk) a[kk] = *(const bf16x8*)&te[arow][kk * 32 + kb0];
  #pragma unroll
  for (int nt = 0; nt < 8; ++nt) {
    int col = nt * 16 + (l & 15);
    const ushort* wcol = wet + (size_t)col * 128 + kb0;
    f32x4 acc = {0.f, 0.f, 0.f, 0.f};
    #pragma unroll
    for (int kk = 0; kk < 4; ++kk) {
      bf16x8 bfr = *(const bf16x8*)(wcol + kk * 32);
      acc = __builtin_amdgcn_mfma_f32_16x16x32_bf16(a[kk], bfr, acc, 0, 0, 0);
    }
    #pragma unroll
    for (int j = 0; j < 4; ++j) {
      long row = e0 + wv * 16 + (l >> 4) * 4 + j;
      if (row < nE) eb[row * 128 + col] = f2b(acc[j]);
    }
  }
}

// fused attention: one wave per dst, 2 edges/iter (lane halves), online softmax
__global__ void k_attn(const int* __restrict__ offs, const int* __restrict__ src_s,
                       const ushort* __restrict__ eb, const ushort* __restrict__ qb,
                       const ushort* __restrict__ kb, const ushort* __restrict__ vb,
                       float* __restrict__ ob, int n) {
  int d = (blockIdx.x * 256 + threadIdx.x) >> 6;
  if (d >= n) return;
  int lane = threadIdx.x & 63;
  int half = lane >> 5;
  int cl = lane & 31;
  int c0 = cl * 4;
  int beg = offs[d], end = offs[d + 1];
  if (beg == end) return;
  uint2 qw = *(const uint2*)(qb + (size_t)d * HID + c0);
  float q0 = blo(qw.x), q1 = bhi(qw.x), q2 = blo(qw.y), q3 = bhi(qw.y);
  float m = -INFINITY, s = 0.f;
  float a0 = 0.f, a1 = 0.f, a2 = 0.f, a3 = 0.f;
  for (int base = beg; base < end; base += 2) {
    int pos = base + half;
    bool valid = pos < end;
    int pp = valid ? pos : end - 1;
    int sv = src_s[pp];
    uint2 kw = *(const uint2*)(kb + (size_t)sv * HID + c0);
    uint2 vw = *(const uint2*)(vb + (size_t)sv * HID + c0);
    uint2 ew = *(const uint2*)(eb + (size_t)pp * HID + c0);
    float e0v = blo(ew.x), e1v = bhi(ew.x), e2v = blo(ew.y), e3v = bhi(ew.y);
    float p = q0 * (blo(kw.x) + e0v) + q1 * (bhi(kw.x) + e1v) +
              q2 * (blo(kw.y) + e2v) + q3 * (bhi(kw.y) + e3v);
    p += __shfl_xor(p, 1);
    p += __shfl_xor(p, 2);
    p += __shfl_xor(p, 4);
    float aSelf = valid ? p * 0.17677669529663687f : -INFINITY;
    float aOth = __shfl_xor(aSelf, 32);
    float nm = fmaxf(m, fmaxf(aSelf, aOth));
    float sc = __expf(m - nm);
    float pe = valid ? __expf(aSelf - nm) : 0.f;
    m = nm;
    s = s * sc + pe;
    a0 = a0 * sc + pe * (blo(vw.x) + e0v);
    a1 = a1 * sc + pe * (bhi(vw.x) + e1v);
    a2 = a2 * sc + pe * (blo(vw.y) + e2v);
    a3 = a3 * sc + pe * (bhi(vw.y) + e3v);
  }
  s += __shfl_xor(s, 32);
  a0 += __shfl_xor(a0, 32);
  a1 += __shfl_xor(a1, 32);
  a2 += __shfl_xor(a2, 32);
  a3 += __shfl_xor(a3, 32);
  if (half == 0) {
    float inv = 1.f / (s + 1e-16f);
    float4* orow = (float4*)(ob + (size_t)d * HID + c0);
    float4 o = *orow;
    o.x += a0 * inv; o.y += a1 * inv; o.z += a2 * inv; o.w += a3 * inv;
    *orow = o;
  }
}

template <bool PRE_RELU>
__global__ void k_bn_reduce(const float* __restrict__ X, int n, int C, int shift,
                            float* __restrict__ sums) {
  int col = threadIdx.x & (C - 1);
  int rloc = threadIdx.x >> shift;
  int rpt = 256 >> shift;
  float s = 0.f, s2 = 0.f;
  for (long r = (long)blockIdx.x * rpt + rloc; r < n; r += (long)gridDim.x * rpt) {
    float v = X[r * C + col];
    if (PRE_RELU) v = v > 0.f ? v : 0.f;
    s += v; s2 += v * v;
  }
  __shared__ float ls[256], ls2[256];
  ls[threadIdx.x] = s; ls2[threadIdx.x] = s2;
  __syncthreads();
  if (rloc == 0) {
    for (int j = 1; j < rpt; ++j) { s += ls[j * C + col]; s2 += ls2[j * C + col]; }
    atomicAdd(&sums[col], s);
    atomicAdd(&sums[C + col], s2);
  }
}

template <bool PRE_RELU, bool POST_RELU, bool BF16OUT>
__global__ void k_bn_apply(const float* __restrict__ X, int n, int C,
                           const float* __restrict__ sums,
                           const float* __restrict__ g, const float* __restrict__ b,
                           void* __restrict__ Yv) {
  long total = (long)n * C;
  float inv_n = 1.f / (float)n;
  for (long i = (long)blockIdx.x * 256 + threadIdx.x; i < total; i += (long)gridDim.x * 256) {
    int col = (int)(i & (C - 1));
    float mean = sums[col] * inv_n;
    float var = sums[C + col] * inv_n - mean * mean;
    float v = X[i];
    if (PRE_RELU) v = v > 0.f ? v : 0.f;
    v = g[col] * (v - mean) * rsqrtf(var + 1e-5f) + b[col];
    if (POST_RELU) v = v > 0.f ? v : 0.f;
    if (BF16OUT) ((ushort*)Yv)[i] = f2b(v);
    else ((float*)Yv)[i] = v;
  }
}

// Y = X @ W + b (X: n x 128 f32, W: 128 x 64), 16 rows/block
__global__ __launch_bounds__(256) void k_gemm_64(
    const float* __restrict__ X, const float* __restrict__ W,
    const float* __restrict__ b, float* __restrict__ Y, int n) {
  __shared__ float xs[16][HID];
  int r0 = blockIdx.x * 16;
  for (int idx = threadIdx.x; idx < 16 * HID; idx += 256) {
    int r = idx >> 7, c = idx & 127;
    int row = r0 + r;
    xs[r][c] = (row < n) ? X[(size_t)row * HID + c] : 0.f;
  }
  __syncthreads();
  int col = threadIdx.x & 63;
  int rg = threadIdx.x >> 6;
  float acc[4] = {0.f, 0.f, 0.f, 0.f};
  #pragma unroll 4
  for (int kk = 0; kk < HID; ++kk) {
    float w = W[kk * 64 + col];
    #pragma unroll
    for (int j = 0; j < 4; ++j) acc[j] += xs[rg + 4 * j][kk] * w;
  }
  float bias = b[col];
  #pragma unroll
  for (int j = 0; j < 4; ++j) {
    int row = r0 + rg + 4 * j;
    if (row < n) Y[(size_t)row * 64 + col] = acc[j] + bias;
  }
}

__global__ __launch_bounds__(256) void k_final(
    const float* __restrict__ z2, const float* __restrict__ W3,
    const float* __restrict__ b3, float* __restrict__ out, int n) {
  int wave = threadIdx.x >> 6, lane = threadIdx.x & 63;
  int row = blockIdx.x * 4 + wave;
  if (row >= n) return;
  float pv = z2[(size_t)row * 64 + lane] * W3[lane];
  pv += __shfl_xor(pv, 1);
  pv += __shfl_xor(pv, 2);
  pv += __shfl_xor(pv, 4);
  pv += __shfl_xor(pv, 8);
  pv += __shfl_xor(pv, 16);
  pv += __shfl_xor(pv, 32);
  if (lane == 0) out[row] = pv + b3[0];
}

extern "C" void kernel_launch(void* const* d_in, const int* in_sizes, int n_in,
                              void* d_out, int out_size, void* d_ws, size_t ws_size,
                              hipStream_t stream) {
  const float* x_all = (const float*)d_in[0];
  const int* ids = (const int*)d_in[1];
  const int* esrc = (const int*)d_in[2];
  const int* edst = (const int*)d_in[3];
  const float* dts = (const float*)d_in[4];
  const float* freq = (const float*)d_in[6];
  const float* phase = (const float*)d_in[7];
  const float* Wp = (const float*)d_in[8];
  const float* bp = (const float*)d_in[9];
  const float* Wq = (const float*)d_in[10];
  const float* bq = (const float*)d_in[11];
  const float* Wk = (const float*)d_in[12];
  const float* bk = (const float*)d_in[13];
  const float* Wv = (const float*)d_in[14];
  const float* bv = (const float*)d_in[15];
  const float* We = (const float*)d_in[16];
  const float* Wskip = (const float*)d_in[17];
  const float* bskip = (const float*)d_in[18];
  const float* bn_g = (const float*)d_in[19];
  const float* bn_b = (const float*)d_in[20];
  const float* W1 = (const float*)d_in[21];
  const float* b1 = (const float*)d_in[22];
  const float* g1 = (const float*)d_in[23];
  const float* be1 = (const float*)d_in[24];
  const float* W2 = (const float*)d_in[25];
  const float* b2 = (const float*)d_in[26];
  const float* g2 = (const float*)d_in[27];
  const float* be2 = (const float*)d_in[28];
  const float* W3 = (const float*)d_in[29];
  const float* b3 = (const float*)d_in[30];

  size_t n = (size_t)in_sizes[1];
  size_t nE = (size_t)in_sizes[2] / 2;
  int B = out_size;

  char* pc = (char*)d_ws;
  auto alloc = [&](size_t bytes) { char* r = pc; pc += (bytes + 255) & ~(size_t)255; return r; };
  ushort* h    = (ushort*)alloc(n * HID * 2);
  ushort* qb   = (ushort*)alloc(n * HID * 2);
  ushort* kb   = (ushort*)alloc(n * HID * 2);
  ushort* vb   = (ushort*)alloc(n * HID * 2);
  float*  ob   = (float*)alloc(n * HID * 4);
  ushort* eb   = (ushort*)alloc(nE * HID * 2);
  int* src_s   = (int*)alloc(nE * 4);
  float* dts_s = (float*)alloc(nE * 4);
  int* counts  = (int*)alloc(n * 4);
  int* cursor  = (int*)alloc(n * 4);
  int* offs    = (int*)alloc((n + 1) * 4);
  int* chunkS  = (int*)alloc(256 * 4);
  ushort* wallT = (ushort*)alloc(512 * 128 * 2);
  float* ball  = (float*)alloc(512 * 4);
  ushort* wet  = (ushort*)alloc(128 * 128 * 2);
  ushort* w1t  = (ushort*)alloc(128 * 128 * 2);
  ushort* wpt  = (ushort*)alloc(128 * KPAD * 2);
  float* sums  = (float*)alloc(256 * 4);
  float* z1    = (float*)alloc((size_t)B * HID * 4);
  float* z2    = (float*)alloc((size_t)B * 64 * 4);

  int gn64 = (int)((n + 63) / 64);
  int gn128 = (int)((n + 127) / 128);
  int ge256 = (int)((nE + 255) / 256);
  int eblk = (int)((nE + 63) / 64);
  int nchunks = (int)((n + 1023) / 1024);

  k_wpt<<<(128 * KPAD + 255) / 256, 256, 0, stream>>>(Wp, wpt);
  k_in_mfma<<<gn64, 256, 0, stream>>>(x_all, ids, wpt, bp, h, (int)n);

  for (int i = 0; i < 2; ++i) {
    const int* src_i = esrc + i * nE;
    const int* dst_i = edst + i * nE;
    const float* dts_i = dts + i * nE;
    const float* We_i = We + (size_t)i * TDIM * HID;

    k_wprep<<<256, 256, 0, stream>>>(Wq + (size_t)i * HID * HID, Wk + (size_t)i * HID * HID,
                                     Wv + (size_t)i * HID * HID, Wskip + (size_t)i * HID * HID,
                                     bq + i * HID, bk + i * HID, bv + i * HID, bskip + i * HID,
                                     wallT, ball);
    k_qkvs<<<gn128, 512, 0, stream>>>(h, wallT, ball, qb, kb, vb, ob, (int)n);

    // counting sort by dst
    hipMemsetAsync(counts, 0, n * 4, stream);
    hipMemsetAsync(cursor, 0, n * 4, stream);
    k_hist<<<ge256, 256, 0, stream>>>(dst_i, counts, (int)nE);
    k_scan_chunk<<<nchunks, 256, 0, stream>>>(counts, offs, chunkS, (int)n);
    k_scan_tops<<<1, 256, 0, stream>>>(chunkS, nchunks);
    k_scan_add<<<(int)((n + 255) / 256), 256, 0, stream>>>(offs, chunkS, (int)n, (int)nE);
    k_scatter<<<ge256, 256, 0, stream>>>(src_i, dst_i, dts_i, offs, cursor, src_s, dts_s, (int)nE);

    // e = cos(dt f + p) @ We, in sorted order
    k_wet<<<64, 256, 0, stream>>>(We_i, wet);
    k_te_mfma<<<eblk, 256, 0, stream>>>(dts_s, freq, phase, wet, eb, (int)nE);

    // fused online-softmax attention, adds into ob (which holds skip)
    k_attn<<<(int)((n + 3) / 4), 256, 0, stream>>>(offs, src_s, eb, qb, kb, vb, ob, (int)n);

    // bn(relu(ob)) -> h (bf16)
    hipMemsetAsync(sums, 0, 2 * HID * sizeof(float), stream);
    k_bn_reduce<true><<<512, 256, 0, stream>>>(ob, (int)n, HID, 7, sums);
    k_bn_apply<true, false, true><<<4096, 256, 0, stream>>>(ob, (int)n, HID, sums,
                                                            bn_g + i * HID, bn_b + i * HID, h);
  }

  // MLP head on first B rows of h
  k_wt128<<<64, 256, 0, stream>>>(W1, w1t);
  k_mfma128<<<(B + 63) / 64, 256, 0, stream>>>(h, w1t, b1, z1, B);
  hipMemsetAsync(sums, 0, 2 * HID * sizeof(float), stream);
  k_bn_reduce<false><<<512, 256, 0, stream>>>(z1, B, HID, 7, sums);
  k_bn_apply<false, true, false><<<2048, 256, 0, stream>>>(z1, B, HID, sums, g1, be1, z1);
  k_gemm_64<<<(B + 15) / 16, 256, 0, stream>>>(z1, W2, b2, z2, B);
  hipMemsetAsync(sums, 0, 2 * 64 * sizeof(float), stream);
  k_bn_reduce<false><<<512, 256, 0, stream>>>(z2, B, 64, 6, sums);
  k_bn_apply<false, true, false><<<2048, 256, 0, stream>>>(z2, B, 64, sums, g2, be2, z2);
  k_final<<<(B + 3) / 4, 256, 0, stream>>>(z2, W3, b3, (float*)d_out, B);
}